// Round 6
// baseline (528.436 us; speedup 1.0000x reference)
//
#include <hip/hip_runtime.h>

// Problem constants (B=8, S=4096, D=64, ds=16)
#define BATCH   8
#define SEQ     4096
#define DM      64
#define DS      16
#define BS      (BATCH*SEQ)      // 32768 timesteps
#define CHUNK   32               // scan chunk length
#define NCH     (SEQ/CHUNK)      // 128 chunks per batch
#define NCH_TOT (BATCH*NCH)      // 1024 chunks total

// ---------------------------------------------------------------------------
// K1a: A = x@WA + bA.  Thread owns output col j = tid; WA col in VGPRs
// (loaded once, coalesced, L2-hot); x rows broadcast from LDS (b128).
// Grid 1024 (32-t tiles).  Per t: 4 ds_read_b128 + 64 VGPR-VGPR FMA + store.
// ---------------------------------------------------------------------------
__global__ __launch_bounds__(256, 2) void k1a_A(
    const float* __restrict__ x, const float* __restrict__ WA,
    const float* __restrict__ bA, float* __restrict__ A_ws)
{
  __shared__ float xs[32][64];   // 8 KB
  const int tid = threadIdx.x;
  const int t0  = blockIdx.x * 32;

  { // stage x tile (coalesced float4)
    const float4* xg = (const float4*)(x + (size_t)t0 * DM);
    float4* xsv = (float4*)&xs[0][0];
    xsv[tid]       = xg[tid];
    xsv[tid + 256] = xg[tid + 256];
  }
  float wcol[64];
  #pragma unroll
  for (int e = 0; e < 64; ++e) wcol[e] = WA[e * 256 + tid];   // coalesced
  const float bias = bA[tid];
  __syncthreads();

  #pragma unroll 1
  for (int t = 0; t < 32; ++t) {
    const float4* xrow = (const float4*)&xs[t][0];
    float z0 = 0.f, z1 = 0.f, z2 = 0.f, z3 = 0.f;
    #pragma unroll
    for (int e4 = 0; e4 < 16; ++e4) {
      float4 xv = xrow[e4];                      // broadcast ds_read_b128
      z0 = fmaf(xv.x, wcol[4*e4+0], z0);
      z1 = fmaf(xv.y, wcol[4*e4+1], z1);
      z2 = fmaf(xv.z, wcol[4*e4+2], z2);
      z3 = fmaf(xv.w, wcol[4*e4+3], z3);
    }
    A_ws[(size_t)(t0 + t) * 256 + tid] = bias + (z0 + z1) + (z2 + z3);
  }
}

// ---------------------------------------------------------------------------
// K1b: Bx[t][n] = x_t^T (bB_n + WB_n x_t).  Wave owns n = q*4+w, lane = d;
// WB column (n,d) in VGPRs.  Per t: 64 FMA -> * x[t][d] -> shfl reduce.
// Grid 1024 = 256 t-blocks (128 t) x 4 q.  Exact (no cross-n sums).
// ---------------------------------------------------------------------------
__global__ __launch_bounds__(256, 2) void k1b_Bx(
    const float* __restrict__ x, const float* __restrict__ WB,
    const float* __restrict__ bB, float* __restrict__ Bx_ws)
{
  __shared__ float xs[128][64];  // 32 KB
  const int tid = threadIdx.x;
  const int d   = tid & 63;
  const int w   = __builtin_amdgcn_readfirstlane(tid >> 6);
  const int q   = blockIdx.x & 3;
  const int t0  = (blockIdx.x >> 2) * 128;
  const int n   = q * 4 + w;

  { // stage x tile
    const float4* xg = (const float4*)(x + (size_t)t0 * DM);
    float4* xsv = (float4*)&xs[0][0];
    #pragma unroll
    for (int i = 0; i < 8; ++i) xsv[tid + 256 * i] = xg[tid + 256 * i];
  }
  float wcol[64];
  #pragma unroll
  for (int e = 0; e < 64; ++e) wcol[e] = WB[e * 1024 + n * 64 + d];  // coalesced
  const float bias = bB[n * 64 + d];
  __syncthreads();

  #pragma unroll 1
  for (int t = 0; t < 128; ++t) {
    const float4* xrow = (const float4*)&xs[t][0];
    float z0 = bias, z1 = 0.f, z2 = 0.f, z3 = 0.f;
    #pragma unroll
    for (int e4 = 0; e4 < 16; ++e4) {
      float4 xv = xrow[e4];                      // broadcast ds_read_b128
      z0 = fmaf(xv.x, wcol[4*e4+0], z0);
      z1 = fmaf(xv.y, wcol[4*e4+1], z1);
      z2 = fmaf(xv.z, wcol[4*e4+2], z2);
      z3 = fmaf(xv.w, wcol[4*e4+3], z3);
    }
    float val = ((z0 + z1) + (z2 + z3)) * xs[t][d];
    #pragma unroll
    for (int off = 32; off; off >>= 1) val += __shfl_xor(val, off, 64);
    if (d == 0) Bx_ws[(size_t)(t0 + t) * DS + n] = val;
  }
}

// ---------------------------------------------------------------------------
// K2: per-chunk cumulative transition with ONE barrier per step.
// ---------------------------------------------------------------------------
__global__ __launch_bounds__(256) void k2_chunk(
    const float* __restrict__ A_ws, const float* __restrict__ Bx_ws,
    float* __restrict__ P_ws, float* __restrict__ v_ws)
{
  __shared__ float Ps[2][16][17];   // +1 pad
  __shared__ float vs[2][16];
  const int tid = threadIdx.x;
  const int i = tid >> 4, j = tid & 15;
  const int chunk = blockIdx.x;
  const int tbase = chunk * CHUNK;

  Ps[0][i][j] = (i == j) ? 1.f : 0.f;
  if (tid < 16) vs[0][tid] = 0.f;
  __syncthreads();

  int cur = 0;
  for (int t = 0; t < CHUNK; ++t) {
    const float4* ar = (const float4*)(A_ws + (size_t)(tbase + t) * 256 + i * 16);
    float4 a0 = ar[0], a1 = ar[1], a2 = ar[2], a3 = ar[3];
    float bx = (j == 0) ? Bx_ws[(size_t)(tbase + t) * DS + i] : 0.f;

    float acc;
    acc  = a0.x*Ps[cur][ 0][j] + a0.y*Ps[cur][ 1][j] + a0.z*Ps[cur][ 2][j] + a0.w*Ps[cur][ 3][j];
    acc += a1.x*Ps[cur][ 4][j] + a1.y*Ps[cur][ 5][j] + a1.z*Ps[cur][ 6][j] + a1.w*Ps[cur][ 7][j];
    acc += a2.x*Ps[cur][ 8][j] + a2.y*Ps[cur][ 9][j] + a2.z*Ps[cur][10][j] + a2.w*Ps[cur][11][j];
    acc += a3.x*Ps[cur][12][j] + a3.y*Ps[cur][13][j] + a3.z*Ps[cur][14][j] + a3.w*Ps[cur][15][j];
    float vacc = 0.f;
    if (j == 0) {
      vacc  = a0.x*vs[cur][ 0] + a0.y*vs[cur][ 1] + a0.z*vs[cur][ 2] + a0.w*vs[cur][ 3];
      vacc += a1.x*vs[cur][ 4] + a1.y*vs[cur][ 5] + a1.z*vs[cur][ 6] + a1.w*vs[cur][ 7];
      vacc += a2.x*vs[cur][ 8] + a2.y*vs[cur][ 9] + a2.z*vs[cur][10] + a2.w*vs[cur][11];
      vacc += a3.x*vs[cur][12] + a3.y*vs[cur][13] + a3.z*vs[cur][14] + a3.w*vs[cur][15];
      vacc += bx;
    }
    Ps[cur ^ 1][i][j] = acc;
    if (j == 0) vs[cur ^ 1][i] = vacc;
    __syncthreads();
    cur ^= 1;
  }
  P_ws[(size_t)chunk * 256 + tid] = Ps[cur][i][j];
  if (tid < 16) v_ws[(size_t)chunk * DS + tid] = vs[cur][tid];
}

// ---------------------------------------------------------------------------
// K3: serial boundary scan across chunks (8 batches x 16 lanes = 128 thr).
// ---------------------------------------------------------------------------
__global__ __launch_bounds__(128) void k3_boundary(
    const float* __restrict__ P_ws, const float* __restrict__ v_ws,
    float* __restrict__ hb_ws)
{
  const int tid = threadIdx.x;
  const int b = tid >> 4;
  const int r = tid & 15;
  float h = 0.f;

  const float4* Pr = (const float4*)&P_ws[(size_t)(b * NCH) * 256 + r * 16];
  float4 c0 = Pr[0], c1 = Pr[1], c2 = Pr[2], c3 = Pr[3];
  float vc = v_ws[(size_t)(b * NCH) * DS + r];

  for (int c = 0; c < NCH; ++c) {
    const int chunk = b * NCH + c;
    float4 n0 = c0, n1 = c1, n2 = c2, n3 = c3; float nv = 0.f;
    if (c < NCH - 1) {
      const float4* Pn = (const float4*)&P_ws[(size_t)(chunk + 1) * 256 + r * 16];
      n0 = Pn[0]; n1 = Pn[1]; n2 = Pn[2]; n3 = Pn[3];
      nv = v_ws[(size_t)(chunk + 1) * DS + r];
    }
    hb_ws[(size_t)chunk * DS + r] = h;
    float acc = vc;
    acc += c0.x*__shfl(h, 0,16) + c0.y*__shfl(h, 1,16) + c0.z*__shfl(h, 2,16) + c0.w*__shfl(h, 3,16);
    acc += c1.x*__shfl(h, 4,16) + c1.y*__shfl(h, 5,16) + c1.z*__shfl(h, 6,16) + c1.w*__shfl(h, 7,16);
    acc += c2.x*__shfl(h, 8,16) + c2.y*__shfl(h, 9,16) + c2.z*__shfl(h,10,16) + c2.w*__shfl(h,11,16);
    acc += c3.x*__shfl(h,12,16) + c3.y*__shfl(h,13,16) + c3.z*__shfl(h,14,16) + c3.w*__shfl(h,15,16);
    h = acc;
    c0 = n0; c1 = n1; c2 = n2; c3 = n3; vc = nv;
  }
}

// ---------------------------------------------------------------------------
// K4: replay scan within each chunk; emit all h_t.  64 thr = 4 x 16 lanes.
// ---------------------------------------------------------------------------
__global__ __launch_bounds__(64) void k4_hs(
    const float* __restrict__ A_ws, const float* __restrict__ Bx_ws,
    const float* __restrict__ hb_ws, float* __restrict__ hs_ws)
{
  const int tid = threadIdx.x;
  const int g = tid >> 4;
  const int r = tid & 15;
  const int chunk = blockIdx.x * 4 + g;
  const int tbase = chunk * CHUNK;

  float h = hb_ws[(size_t)chunk * DS + r];
  float4 pa[4][4];
  float pbx[4];
  #pragma unroll
  for (int s = 0; s < 4; ++s) {
    const float4* Arow = (const float4*)&A_ws[(size_t)(tbase + s) * 256 + r * 16];
    pa[s][0] = Arow[0]; pa[s][1] = Arow[1]; pa[s][2] = Arow[2]; pa[s][3] = Arow[3];
    pbx[s] = Bx_ws[(size_t)(tbase + s) * DS + r];
  }

  for (int t = 0; t < CHUNK; t += 4) {
    #pragma unroll
    for (int u = 0; u < 4; ++u) {
      const int tt = t + u;
      float4 q0 = pa[u][0], q1 = pa[u][1], q2 = pa[u][2], q3 = pa[u][3];
      float acc = pbx[u];
      if (tt + 4 < CHUNK) {
        const float4* Arow = (const float4*)&A_ws[(size_t)(tbase + tt + 4) * 256 + r * 16];
        pa[u][0] = Arow[0]; pa[u][1] = Arow[1]; pa[u][2] = Arow[2]; pa[u][3] = Arow[3];
        pbx[u] = Bx_ws[(size_t)(tbase + tt + 4) * DS + r];
      }
      acc += q0.x*__shfl(h, 0,16) + q0.y*__shfl(h, 1,16) + q0.z*__shfl(h, 2,16) + q0.w*__shfl(h, 3,16);
      acc += q1.x*__shfl(h, 4,16) + q1.y*__shfl(h, 5,16) + q1.z*__shfl(h, 6,16) + q1.w*__shfl(h, 7,16);
      acc += q2.x*__shfl(h, 8,16) + q2.y*__shfl(h, 9,16) + q2.z*__shfl(h,10,16) + q2.w*__shfl(h,11,16);
      acc += q3.x*__shfl(h,12,16) + q3.y*__shfl(h,13,16) + q3.z*__shfl(h,14,16) + q3.w*__shfl(h,15,16);
      hs_ws[(size_t)(tbase + tt) * DS + r] = acc;
      h = acc;
    }
  }
}

// ---------------------------------------------------------------------------
// K5: out[t][d] = sum_n h[t][n]*(bC[n,d] + sum_e x[t,e] WC[e,n*64+d]).
// 4-wave block, 32-t tile; loop q: wave w does n=q*4+w with WC col in VGPRs
// (reloaded per q, L2-hot); contributions summed in LDS acc via ds_add.
// Grid 1024.
// ---------------------------------------------------------------------------
__global__ __launch_bounds__(256, 2) void k5_out(
    const float* __restrict__ x, const float* __restrict__ WC,
    const float* __restrict__ bC, const float* __restrict__ hs_ws,
    float* __restrict__ out)
{
  __shared__ float xs[32][64];    // 8 KB
  __shared__ float acc[32][64];   // 8 KB
  const int tid = threadIdx.x;
  const int d   = tid & 63;
  const int w   = __builtin_amdgcn_readfirstlane(tid >> 6);
  const int t0  = blockIdx.x * 32;

  { // stage x tile + zero acc
    const float4* xg = (const float4*)(x + (size_t)t0 * DM);
    float4* xsv = (float4*)&xs[0][0];
    float4* av  = (float4*)&acc[0][0];
    xsv[tid]       = xg[tid];
    xsv[tid + 256] = xg[tid + 256];
    av[tid]        = make_float4(0.f, 0.f, 0.f, 0.f);
    av[tid + 256]  = make_float4(0.f, 0.f, 0.f, 0.f);
  }
  __syncthreads();

  #pragma unroll 1
  for (int q = 0; q < 4; ++q) {
    const int n = q * 4 + w;
    float wcol[64];
    #pragma unroll
    for (int e = 0; e < 64; ++e) wcol[e] = WC[e * 1024 + n * 64 + d];  // coalesced
    const float bias = bC[n * 64 + d];
    #pragma unroll 1
    for (int t = 0; t < 32; ++t) {
      const float4* xrow = (const float4*)&xs[t][0];
      float z0 = bias, z1 = 0.f, z2 = 0.f, z3 = 0.f;
      #pragma unroll
      for (int e4 = 0; e4 < 16; ++e4) {
        float4 xv = xrow[e4];                    // broadcast ds_read_b128
        z0 = fmaf(xv.x, wcol[4*e4+0], z0);
        z1 = fmaf(xv.y, wcol[4*e4+1], z1);
        z2 = fmaf(xv.z, wcol[4*e4+2], z2);
        z3 = fmaf(xv.w, wcol[4*e4+3], z3);
      }
      const float hn = hs_ws[(size_t)(t0 + t) * DS + n];   // uniform s_load
      atomicAdd(&acc[t][d], hn * ((z0 + z1) + (z2 + z3))); // ds_add_f32
    }
  }
  __syncthreads();

  { // coalesced float4 out
    const float4* av = (const float4*)&acc[0][0];
    float4* og = (float4*)(out + (size_t)t0 * DM);
    og[tid]       = av[tid];
    og[tid + 256] = av[tid + 256];
  }
}

// ---------------------------------------------------------------------------
extern "C" void kernel_launch(void* const* d_in, const int* in_sizes, int n_in,
                              void* d_out, int out_size, void* d_ws, size_t ws_size,
                              hipStream_t stream) {
  const float* x  = (const float*)d_in[0];
  const float* WA = (const float*)d_in[1];
  const float* bA = (const float*)d_in[2];
  const float* WB = (const float*)d_in[3];
  const float* bB = (const float*)d_in[4];
  const float* WC = (const float*)d_in[5];
  const float* bC = (const float*)d_in[6];
  float* out = (float*)d_out;

  float* ws    = (float*)d_ws;
  float* A_ws  = ws;                              // 32768*256
  float* Bx_ws = A_ws  + (size_t)BS * 256;        // 32768*16
  float* P_ws  = Bx_ws + (size_t)BS * DS;         // 1024*256
  float* v_ws  = P_ws  + (size_t)NCH_TOT * 256;   // 1024*16
  float* hb_ws = v_ws  + (size_t)NCH_TOT * DS;    // 1024*16
  float* hs_ws = hb_ws + (size_t)NCH_TOT * DS;    // 32768*16

  k1a_A      <<<BS / 32,           256, 0, stream>>>(x, WA, bA, A_ws);
  k1b_Bx     <<<(BS / 128) * 4,    256, 0, stream>>>(x, WB, bB, Bx_ws);
  k2_chunk   <<<NCH_TOT,           256, 0, stream>>>(A_ws, Bx_ws, P_ws, v_ws);
  k3_boundary<<<1,                 128, 0, stream>>>(P_ws, v_ws, hb_ws);
  k4_hs      <<<NCH_TOT / 4,        64, 0, stream>>>(A_ws, Bx_ws, hb_ws, hs_ws);
  k5_out     <<<BS / 32,           256, 0, stream>>>(x, WC, bC, hs_ws, out);
}

// Round 7
// 229.241 us; speedup vs baseline: 2.3052x; 2.3052x over previous
//
#include <hip/hip_runtime.h>

// Problem constants (B=8, S=4096, D=64, ds=16)
#define BATCH   8
#define SEQ     4096
#define DM      64
#define DS      16
#define BS      (BATCH*SEQ)      // 32768 timesteps
#define CHUNK   32               // scan chunk length
#define NCH     (SEQ/CHUNK)      // 128 chunks per batch
#define NCH_TOT (BATCH*NCH)      // 1024 chunks total

typedef __attribute__((ext_vector_type(8))) __bf16 bf16x8;
typedef __attribute__((ext_vector_type(4))) float  f32x4;

__device__ __forceinline__ unsigned short f2bf(float f) {
  unsigned int u = __float_as_uint(f);
  u += 0x7fffu + ((u >> 16) & 1u);          // RNE (finite values)
  return (unsigned short)(u >> 16);
}

// ---------------------------------------------------------------------------
// K0x: cast x (fp32) -> xb (bf16).  8 elems/thread, 1024 blocks.
// ---------------------------------------------------------------------------
__global__ __launch_bounds__(256) void k0_castx(
    const float* __restrict__ x, unsigned short* __restrict__ xb)
{
  const int i = (blockIdx.x * 256 + threadIdx.x) * 8;
  float4 v0 = *(const float4*)(x + i);
  float4 v1 = *(const float4*)(x + i + 4);
  ushort4 o0 = {f2bf(v0.x), f2bf(v0.y), f2bf(v0.z), f2bf(v0.w)};
  ushort4 o1 = {f2bf(v1.x), f2bf(v1.y), f2bf(v1.z), f2bf(v1.w)};
  *(ushort4*)(xb + i)     = o0;
  *(ushort4*)(xb + i + 4) = o1;
}

// ---------------------------------------------------------------------------
// K0w: transpose+cast weights.  WAt[j][e]=WA[e][j] (256x64),
// WBt[c][e]=WB[e][c] (1024x64), WCt likewise.  One elem/thread, 576 blocks.
// ---------------------------------------------------------------------------
__global__ __launch_bounds__(256) void k0_castw(
    const float* __restrict__ WA, const float* __restrict__ WB,
    const float* __restrict__ WC,
    unsigned short* __restrict__ WAt, unsigned short* __restrict__ WBt,
    unsigned short* __restrict__ WCt)
{
  const int o = blockIdx.x * 256 + threadIdx.x;
  if (o < 16384) {
    const int c = o >> 6, e = o & 63;
    WAt[o] = f2bf(WA[e * 256 + c]);
  } else if (o < 16384 + 65536) {
    const int p = o - 16384;
    const int c = p >> 6, e = p & 63;
    WBt[p] = f2bf(WB[e * 1024 + c]);
  } else {
    const int p = o - 16384 - 65536;
    const int c = p >> 6, e = p & 63;
    WCt[p] = f2bf(WC[e * 1024 + c]);
  }
}

// ---------------------------------------------------------------------------
// GEMM-A: A_ws[t][j] = x_t . WA[:,j] + bA[j].  MFMA 16x16x32 bf16.
// 512 blocks x 4 waves; wave w owns t-subtile [t0+w*16, +16), loops 16
// N-subtiles.  A/B frags straight from global (L2-hot).  fp32 out.
// ---------------------------------------------------------------------------
__global__ __launch_bounds__(256) void g_A(
    const unsigned short* __restrict__ xb, const unsigned short* __restrict__ WAt,
    const float* __restrict__ bA, float* __restrict__ A_ws)
{
  const int tid  = threadIdx.x;
  const int lane = tid & 63;
  const int l15  = lane & 15;
  const int quad = lane >> 4;
  const int w    = tid >> 6;
  const int t0   = blockIdx.x * 64;
  const int tw   = t0 + w * 16;

  const bf16x8* xv = (const bf16x8*)(xb + (size_t)(tw + l15) * 64);
  bf16x8 a0 = xv[quad];       // k = quad*8 .. +7
  bf16x8 a1 = xv[quad + 4];   // k = 32 + quad*8 .. +7

  #pragma unroll 1
  for (int ns = 0; ns < 16; ++ns) {
    const bf16x8* wv = (const bf16x8*)(WAt + (size_t)(ns * 16 + l15) * 64);
    f32x4 acc = {0.f, 0.f, 0.f, 0.f};
    acc = __builtin_amdgcn_mfma_f32_16x16x32_bf16(a0, wv[quad],     acc, 0, 0, 0);
    acc = __builtin_amdgcn_mfma_f32_16x16x32_bf16(a1, wv[quad + 4], acc, 0, 0, 0);
    const float bias = bA[ns * 16 + l15];
    #pragma unroll
    for (int r = 0; r < 4; ++r)
      A_ws[(size_t)(tw + quad * 4 + r) * 256 + ns * 16 + l15] = acc[r] + bias;
  }
}

// ---------------------------------------------------------------------------
// GEMM-B fused: Bm = x@WB + bB (never stored); Bx[t][n] = sum_d Bm[t,n,d]*x[t,d].
// Same tiling as g_A over N=1024 (16 n x 4 d-subtiles).  Epilogue contracts
// with fp32 x (LDS) and shuffle-reduces over the 16 d-lanes.
// ---------------------------------------------------------------------------
__global__ __launch_bounds__(256) void g_B(
    const unsigned short* __restrict__ xb, const unsigned short* __restrict__ WBt,
    const float* __restrict__ bB, const float* __restrict__ x,
    float* __restrict__ Bx_ws)
{
  __shared__ float xs[64][68];   // fp32 x tile for epilogue (16B-aligned rows)
  __shared__ float bBs[1024];
  const int tid  = threadIdx.x;
  const int lane = tid & 63;
  const int l15  = lane & 15;
  const int quad = lane >> 4;
  const int w    = tid >> 6;
  const int t0   = blockIdx.x * 64;
  const int tw   = t0 + w * 16;

  { // stage x fp32 (64x64) and bB
    const float4* xg = (const float4*)(x + (size_t)t0 * DM);
    #pragma unroll
    for (int i = 0; i < 4; ++i) {
      const int f4 = tid + 256 * i;
      ((float4*)&xs[f4 >> 4][0])[f4 & 15] = xg[f4];
    }
    ((float4*)bBs)[tid] = ((const float4*)bB)[tid];
  }

  const bf16x8* xv = (const bf16x8*)(xb + (size_t)(tw + l15) * 64);
  bf16x8 a0 = xv[quad];
  bf16x8 a1 = xv[quad + 4];
  __syncthreads();

  #pragma unroll 1
  for (int n = 0; n < 16; ++n) {
    f32x4 ac[4];
    #pragma unroll
    for (int r = 0; r < 4; ++r) {
      const bf16x8* wv = (const bf16x8*)(WBt + (size_t)((n * 4 + r) * 16 + l15) * 64);
      f32x4 t = {0.f, 0.f, 0.f, 0.f};
      t = __builtin_amdgcn_mfma_f32_16x16x32_bf16(a0, wv[quad],     t, 0, 0, 0);
      t = __builtin_amdgcn_mfma_f32_16x16x32_bf16(a1, wv[quad + 4], t, 0, 0, 0);
      ac[r] = t;
    }
    // epilogue: part[reg] = sum_r (ac[r][reg] + bB[n, r*16+l15]) * x[t, r*16+l15]
    float part[4] = {0.f, 0.f, 0.f, 0.f};
    #pragma unroll
    for (int r = 0; r < 4; ++r) {
      const float bb = bBs[n * 64 + r * 16 + l15];
      #pragma unroll
      for (int reg = 0; reg < 4; ++reg) {
        const int tl = w * 16 + quad * 4 + reg;
        part[reg] = fmaf(ac[r][reg] + bb, xs[tl][r * 16 + l15], part[reg]);
      }
    }
    #pragma unroll
    for (int off = 1; off < 16; off <<= 1) {
      #pragma unroll
      for (int reg = 0; reg < 4; ++reg)
        part[reg] += __shfl_xor(part[reg], off, 64);
    }
    if (l15 == 0) {
      #pragma unroll
      for (int reg = 0; reg < 4; ++reg)
        Bx_ws[(size_t)(tw + quad * 4 + reg) * DS + n] = part[reg];
    }
  }
}

// ---------------------------------------------------------------------------
// K2: per-chunk cumulative transition (fp32), one barrier per step.
// ---------------------------------------------------------------------------
__global__ __launch_bounds__(256) void k2_chunk(
    const float* __restrict__ A_ws, const float* __restrict__ Bx_ws,
    float* __restrict__ P_ws, float* __restrict__ v_ws)
{
  __shared__ float Ps[2][16][17];
  __shared__ float vs[2][16];
  const int tid = threadIdx.x;
  const int i = tid >> 4, j = tid & 15;
  const int chunk = blockIdx.x;
  const int tbase = chunk * CHUNK;

  Ps[0][i][j] = (i == j) ? 1.f : 0.f;
  if (tid < 16) vs[0][tid] = 0.f;
  __syncthreads();

  int cur = 0;
  for (int t = 0; t < CHUNK; ++t) {
    const float4* ar = (const float4*)(A_ws + (size_t)(tbase + t) * 256 + i * 16);
    float4 a0 = ar[0], a1 = ar[1], a2 = ar[2], a3 = ar[3];
    float bx = (j == 0) ? Bx_ws[(size_t)(tbase + t) * DS + i] : 0.f;

    float acc;
    acc  = a0.x*Ps[cur][ 0][j] + a0.y*Ps[cur][ 1][j] + a0.z*Ps[cur][ 2][j] + a0.w*Ps[cur][ 3][j];
    acc += a1.x*Ps[cur][ 4][j] + a1.y*Ps[cur][ 5][j] + a1.z*Ps[cur][ 6][j] + a1.w*Ps[cur][ 7][j];
    acc += a2.x*Ps[cur][ 8][j] + a2.y*Ps[cur][ 9][j] + a2.z*Ps[cur][10][j] + a2.w*Ps[cur][11][j];
    acc += a3.x*Ps[cur][12][j] + a3.y*Ps[cur][13][j] + a3.z*Ps[cur][14][j] + a3.w*Ps[cur][15][j];
    float vacc = 0.f;
    if (j == 0) {
      vacc  = a0.x*vs[cur][ 0] + a0.y*vs[cur][ 1] + a0.z*vs[cur][ 2] + a0.w*vs[cur][ 3];
      vacc += a1.x*vs[cur][ 4] + a1.y*vs[cur][ 5] + a1.z*vs[cur][ 6] + a1.w*vs[cur][ 7];
      vacc += a2.x*vs[cur][ 8] + a2.y*vs[cur][ 9] + a2.z*vs[cur][10] + a2.w*vs[cur][11];
      vacc += a3.x*vs[cur][12] + a3.y*vs[cur][13] + a3.z*vs[cur][14] + a3.w*vs[cur][15];
      vacc += bx;
    }
    Ps[cur ^ 1][i][j] = acc;
    if (j == 0) vs[cur ^ 1][i] = vacc;
    __syncthreads();
    cur ^= 1;
  }
  P_ws[(size_t)chunk * 256 + tid] = Ps[cur][i][j];
  if (tid < 16) v_ws[(size_t)chunk * DS + tid] = vs[cur][tid];
}

// ---------------------------------------------------------------------------
// K3: serial boundary scan across chunks (8 batches x 16 lanes = 128 thr).
// ---------------------------------------------------------------------------
__global__ __launch_bounds__(128) void k3_boundary(
    const float* __restrict__ P_ws, const float* __restrict__ v_ws,
    float* __restrict__ hb_ws)
{
  const int tid = threadIdx.x;
  const int b = tid >> 4;
  const int r = tid & 15;
  float h = 0.f;

  const float4* Pr = (const float4*)&P_ws[(size_t)(b * NCH) * 256 + r * 16];
  float4 c0 = Pr[0], c1 = Pr[1], c2 = Pr[2], c3 = Pr[3];
  float vc = v_ws[(size_t)(b * NCH) * DS + r];

  for (int c = 0; c < NCH; ++c) {
    const int chunk = b * NCH + c;
    float4 n0 = c0, n1 = c1, n2 = c2, n3 = c3; float nv = 0.f;
    if (c < NCH - 1) {
      const float4* Pn = (const float4*)&P_ws[(size_t)(chunk + 1) * 256 + r * 16];
      n0 = Pn[0]; n1 = Pn[1]; n2 = Pn[2]; n3 = Pn[3];
      nv = v_ws[(size_t)(chunk + 1) * DS + r];
    }
    hb_ws[(size_t)chunk * DS + r] = h;
    float acc = vc;
    acc += c0.x*__shfl(h, 0,16) + c0.y*__shfl(h, 1,16) + c0.z*__shfl(h, 2,16) + c0.w*__shfl(h, 3,16);
    acc += c1.x*__shfl(h, 4,16) + c1.y*__shfl(h, 5,16) + c1.z*__shfl(h, 6,16) + c1.w*__shfl(h, 7,16);
    acc += c2.x*__shfl(h, 8,16) + c2.y*__shfl(h, 9,16) + c2.z*__shfl(h,10,16) + c2.w*__shfl(h,11,16);
    acc += c3.x*__shfl(h,12,16) + c3.y*__shfl(h,13,16) + c3.z*__shfl(h,14,16) + c3.w*__shfl(h,15,16);
    h = acc;
    c0 = n0; c1 = n1; c2 = n2; c3 = n3; vc = nv;
  }
}

// ---------------------------------------------------------------------------
// K4: replay scan within each chunk; emit all h_t.  64 thr = 4 x 16 lanes.
// ---------------------------------------------------------------------------
__global__ __launch_bounds__(64) void k4_hs(
    const float* __restrict__ A_ws, const float* __restrict__ Bx_ws,
    const float* __restrict__ hb_ws, float* __restrict__ hs_ws)
{
  const int tid = threadIdx.x;
  const int g = tid >> 4;
  const int r = tid & 15;
  const int chunk = blockIdx.x * 4 + g;
  const int tbase = chunk * CHUNK;

  float h = hb_ws[(size_t)chunk * DS + r];
  float4 pa[4][4];
  float pbx[4];
  #pragma unroll
  for (int s = 0; s < 4; ++s) {
    const float4* Arow = (const float4*)&A_ws[(size_t)(tbase + s) * 256 + r * 16];
    pa[s][0] = Arow[0]; pa[s][1] = Arow[1]; pa[s][2] = Arow[2]; pa[s][3] = Arow[3];
    pbx[s] = Bx_ws[(size_t)(tbase + s) * DS + r];
  }

  for (int t = 0; t < CHUNK; t += 4) {
    #pragma unroll
    for (int u = 0; u < 4; ++u) {
      const int tt = t + u;
      float4 q0 = pa[u][0], q1 = pa[u][1], q2 = pa[u][2], q3 = pa[u][3];
      float acc = pbx[u];
      if (tt + 4 < CHUNK) {
        const float4* Arow = (const float4*)&A_ws[(size_t)(tbase + tt + 4) * 256 + r * 16];
        pa[u][0] = Arow[0]; pa[u][1] = Arow[1]; pa[u][2] = Arow[2]; pa[u][3] = Arow[3];
        pbx[u] = Bx_ws[(size_t)(tbase + tt + 4) * DS + r];
      }
      acc += q0.x*__shfl(h, 0,16) + q0.y*__shfl(h, 1,16) + q0.z*__shfl(h, 2,16) + q0.w*__shfl(h, 3,16);
      acc += q1.x*__shfl(h, 4,16) + q1.y*__shfl(h, 5,16) + q1.z*__shfl(h, 6,16) + q1.w*__shfl(h, 7,16);
      acc += q2.x*__shfl(h, 8,16) + q2.y*__shfl(h, 9,16) + q2.z*__shfl(h,10,16) + q2.w*__shfl(h,11,16);
      acc += q3.x*__shfl(h,12,16) + q3.y*__shfl(h,13,16) + q3.z*__shfl(h,14,16) + q3.w*__shfl(h,15,16);
      hs_ws[(size_t)(tbase + tt) * DS + r] = acc;
      h = acc;
    }
  }
}

// ---------------------------------------------------------------------------
// GEMM-C fused: z = x@WC + bC (never stored); out[t][d] = sum_n z[t,n,d]*h[t,n].
// Same tiling as g_B; epilogue multiplies by h (LDS) and accumulates over n
// into 16 registers per lane; direct global stores.
// ---------------------------------------------------------------------------
__global__ __launch_bounds__(256) void g_C(
    const unsigned short* __restrict__ xb, const unsigned short* __restrict__ WCt,
    const float* __restrict__ bC, const float* __restrict__ hs_ws,
    float* __restrict__ out)
{
  __shared__ float hsh[64][17];
  __shared__ float bCs[1024];
  const int tid  = threadIdx.x;
  const int lane = tid & 63;
  const int l15  = lane & 15;
  const int quad = lane >> 4;
  const int w    = tid >> 6;
  const int t0   = blockIdx.x * 64;
  const int tw   = t0 + w * 16;

  { // stage h tile (64x16) and bC
    float4 hv = ((const float4*)(hs_ws + (size_t)t0 * DS))[tid];
    const int t = tid >> 2, n0 = (tid & 3) * 4;
    hsh[t][n0] = hv.x; hsh[t][n0+1] = hv.y; hsh[t][n0+2] = hv.z; hsh[t][n0+3] = hv.w;
    ((float4*)bCs)[tid] = ((const float4*)bC)[tid];
  }

  const bf16x8* xv = (const bf16x8*)(xb + (size_t)(tw + l15) * 64);
  bf16x8 a0 = xv[quad];
  bf16x8 a1 = xv[quad + 4];
  __syncthreads();

  f32x4 ota[4];   // [r][reg] : d = r*16+l15, t = tw + quad*4 + reg
  #pragma unroll
  for (int r = 0; r < 4; ++r) ota[r] = (f32x4){0.f, 0.f, 0.f, 0.f};

  #pragma unroll 1
  for (int n = 0; n < 16; ++n) {
    f32x4 ac[4];
    #pragma unroll
    for (int r = 0; r < 4; ++r) {
      const bf16x8* wv = (const bf16x8*)(WCt + (size_t)((n * 4 + r) * 16 + l15) * 64);
      f32x4 t = {0.f, 0.f, 0.f, 0.f};
      t = __builtin_amdgcn_mfma_f32_16x16x32_bf16(a0, wv[quad],     t, 0, 0, 0);
      t = __builtin_amdgcn_mfma_f32_16x16x32_bf16(a1, wv[quad + 4], t, 0, 0, 0);
      ac[r] = t;
    }
    float hn[4];
    #pragma unroll
    for (int reg = 0; reg < 4; ++reg) hn[reg] = hsh[w * 16 + quad * 4 + reg][n];
    #pragma unroll
    for (int r = 0; r < 4; ++r) {
      const float bc = bCs[n * 64 + r * 16 + l15];
      #pragma unroll
      for (int reg = 0; reg < 4; ++reg)
        ota[r][reg] = fmaf(ac[r][reg] + bc, hn[reg], ota[r][reg]);
    }
  }

  #pragma unroll
  for (int r = 0; r < 4; ++r)
    #pragma unroll
    for (int reg = 0; reg < 4; ++reg)
      out[(size_t)(tw + quad * 4 + reg) * DM + r * 16 + l15] = ota[r][reg];
}

// ---------------------------------------------------------------------------
extern "C" void kernel_launch(void* const* d_in, const int* in_sizes, int n_in,
                              void* d_out, int out_size, void* d_ws, size_t ws_size,
                              hipStream_t stream) {
  const float* x  = (const float*)d_in[0];
  const float* WA = (const float*)d_in[1];
  const float* bA = (const float*)d_in[2];
  const float* WB = (const float*)d_in[3];
  const float* bB = (const float*)d_in[4];
  const float* WC = (const float*)d_in[5];
  const float* bC = (const float*)d_in[6];
  float* out = (float*)d_out;

  float* ws    = (float*)d_ws;
  float* A_ws  = ws;                              // 8,388,608 f
  float* Bx_ws = A_ws  + (size_t)BS * 256;        //   524,288 f
  float* P_ws  = Bx_ws + (size_t)BS * DS;         //   262,144 f
  float* v_ws  = P_ws  + (size_t)NCH_TOT * 256;   //    16,384 f
  float* hb_ws = v_ws  + (size_t)NCH_TOT * DS;    //    16,384 f
  float* hs_ws = hb_ws + (size_t)NCH_TOT * DS;    //   524,288 f
  unsigned short* xb  = (unsigned short*)(hs_ws + (size_t)BS * DS); // 2,097,152 us
  unsigned short* WAt = xb  + (size_t)BS * 64;    //  16,384 us
  unsigned short* WBt = WAt + 256 * 64;           //  65,536 us
  unsigned short* WCt = WBt + 1024 * 64;          //  65,536 us
  // total ~43.4 MB

  k0_castx   <<<BS * 64 / (256 * 8), 256, 0, stream>>>(x, xb);
  k0_castw   <<<576,                 256, 0, stream>>>(WA, WB, WC, WAt, WBt, WCt);
  g_A        <<<BS / 64,             256, 0, stream>>>(xb, WAt, bA, A_ws);
  g_B        <<<BS / 64,             256, 0, stream>>>(xb, WBt, bB, x, Bx_ws);
  k2_chunk   <<<NCH_TOT,             256, 0, stream>>>(A_ws, Bx_ws, P_ws, v_ws);
  k3_boundary<<<1,                   128, 0, stream>>>(P_ws, v_ws, hb_ws);
  k4_hs      <<<NCH_TOT / 4,          64, 0, stream>>>(A_ws, Bx_ws, hb_ws, hs_ws);
  g_C        <<<BS / 64,             256, 0, stream>>>(xb, WCt, bC, hs_ws, out);
}

// Round 8
// 212.386 us; speedup vs baseline: 2.4881x; 1.0794x over previous
//
#include <hip/hip_runtime.h>

// Problem constants (B=8, S=4096, D=64, ds=16)
#define BATCH   8
#define SEQ     4096
#define DM      64
#define DS      16
#define BS      (BATCH*SEQ)      // 32768 timesteps
#define CHUNK   32               // scan chunk length
#define NCH     (SEQ/CHUNK)      // 128 chunks per batch
#define NCH_TOT (BATCH*NCH)      // 1024 chunks total

typedef __attribute__((ext_vector_type(8))) __bf16 bf16x8;
typedef __attribute__((ext_vector_type(4))) float  f32x4;

__device__ __forceinline__ unsigned short f2bf(float f) {
  unsigned int u = __float_as_uint(f);
  u += 0x7fffu + ((u >> 16) & 1u);          // RNE (finite values)
  return (unsigned short)(u >> 16);
}
__device__ __forceinline__ float bflo(unsigned int u) { return __uint_as_float(u << 16); }
__device__ __forceinline__ float bfhi(unsigned int u) { return __uint_as_float(u & 0xffff0000u); }

// LDS A-tile strides (ushorts): b64-aligned rows, bank-spread
#define AS_I 20                 // per-i stride (40 B)
#define AS_T 324                // per-t stride (648 B; 16*20+4 pad)

// ---------------------------------------------------------------------------
// K0: cast x -> bf16 (blocks 0..1023) and transpose+cast weights
// (blocks 1024..1599).  WAt[j][e]=WA[e][j]; WBt/WCt likewise (1024x64).
// ---------------------------------------------------------------------------
__global__ __launch_bounds__(256) void k0_cast(
    const float* __restrict__ x, const float* __restrict__ WA,
    const float* __restrict__ WB, const float* __restrict__ WC,
    unsigned short* __restrict__ xb, unsigned short* __restrict__ WAt,
    unsigned short* __restrict__ WBt, unsigned short* __restrict__ WCt)
{
  const int b = blockIdx.x;
  if (b < 1024) {
    const int i = (b * 256 + threadIdx.x) * 8;
    float4 v0 = *(const float4*)(x + i);
    float4 v1 = *(const float4*)(x + i + 4);
    ushort4 o0 = {f2bf(v0.x), f2bf(v0.y), f2bf(v0.z), f2bf(v0.w)};
    ushort4 o1 = {f2bf(v1.x), f2bf(v1.y), f2bf(v1.z), f2bf(v1.w)};
    *(ushort4*)(xb + i)     = o0;
    *(ushort4*)(xb + i + 4) = o1;
  } else {
    const int o = (b - 1024) * 256 + threadIdx.x;
    if (o < 16384) {
      const int c = o >> 6, e = o & 63;
      WAt[o] = f2bf(WA[e * 256 + c]);
    } else if (o < 16384 + 65536) {
      const int p = o - 16384;
      const int c = p >> 6, e = p & 63;
      WBt[p] = f2bf(WB[e * 1024 + c]);
    } else {
      const int p = o - 16384 - 65536;
      const int c = p >> 6, e = p & 63;
      WCt[p] = f2bf(WC[e * 1024 + c]);
    }
  }
}

// ---------------------------------------------------------------------------
// GEMM-B fused: Bm = x@WB + bB (never stored); Bx[t][n] = sum_d Bm[t,n,d]*x[t,d].
// ---------------------------------------------------------------------------
__global__ __launch_bounds__(256) void g_B(
    const unsigned short* __restrict__ xb, const unsigned short* __restrict__ WBt,
    const float* __restrict__ bB, const float* __restrict__ x,
    float* __restrict__ Bx_ws)
{
  __shared__ float xs[64][68];
  __shared__ float bBs[1024];
  const int tid  = threadIdx.x;
  const int lane = tid & 63;
  const int l15  = lane & 15;
  const int quad = lane >> 4;
  const int w    = tid >> 6;
  const int t0   = blockIdx.x * 64;
  const int tw   = t0 + w * 16;

  {
    const float4* xg = (const float4*)(x + (size_t)t0 * DM);
    #pragma unroll
    for (int i = 0; i < 4; ++i) {
      const int f4 = tid + 256 * i;
      ((float4*)&xs[f4 >> 4][0])[f4 & 15] = xg[f4];
    }
    ((float4*)bBs)[tid] = ((const float4*)bB)[tid];
  }

  const bf16x8* xv = (const bf16x8*)(xb + (size_t)(tw + l15) * 64);
  bf16x8 a0 = xv[quad];
  bf16x8 a1 = xv[quad + 4];
  __syncthreads();

  #pragma unroll 2
  for (int n = 0; n < 16; ++n) {
    f32x4 ac[4];
    #pragma unroll
    for (int r = 0; r < 4; ++r) {
      const bf16x8* wv = (const bf16x8*)(WBt + (size_t)((n * 4 + r) * 16 + l15) * 64);
      f32x4 t = {0.f, 0.f, 0.f, 0.f};
      t = __builtin_amdgcn_mfma_f32_16x16x32_bf16(a0, wv[quad],     t, 0, 0, 0);
      t = __builtin_amdgcn_mfma_f32_16x16x32_bf16(a1, wv[quad + 4], t, 0, 0, 0);
      ac[r] = t;
    }
    float part[4] = {0.f, 0.f, 0.f, 0.f};
    #pragma unroll
    for (int r = 0; r < 4; ++r) {
      const float bb = bBs[n * 64 + r * 16 + l15];
      #pragma unroll
      for (int reg = 0; reg < 4; ++reg) {
        const int tl = w * 16 + quad * 4 + reg;
        part[reg] = fmaf(ac[r][reg] + bb, xs[tl][r * 16 + l15], part[reg]);
      }
    }
    #pragma unroll
    for (int off = 1; off < 16; off <<= 1) {
      #pragma unroll
      for (int reg = 0; reg < 4; ++reg)
        part[reg] += __shfl_xor(part[reg], off, 64);
    }
    if (l15 == 0) {
      #pragma unroll
      for (int reg = 0; reg < 4; ++reg)
        Bx_ws[(size_t)(tw + quad * 4 + reg) * DS + n] = part[reg];
    }
  }
}

// ---------------------------------------------------------------------------
// GK2 (fused A-GEMM + chunk scan): per block = 64 t = 2 chunks.
// Phase 1 (4 waves): A-tile via MFMA -> LDS bf16 (layout As[t][i][k]).
// Phase 2 (waves 0,1; wave w = chunk): sequential over 32 steps:
//   W <- A_t * W  (mfma 16x16x32; C-frag -> B-frag via 8 shuffles)
//   u <- A_t * u + Bx_t  (fp32 VALU, u in LDS)
// writes per-t prefix W_t (bf16, into As in place) + u_t; chunk P,v at end.
// Phase 3 (all waves): coalesced flush of W tile to global.
// ---------------------------------------------------------------------------
__global__ __launch_bounds__(256) void gk2(
    const unsigned short* __restrict__ xb, const unsigned short* __restrict__ WAt,
    const float* __restrict__ bA, const float* __restrict__ Bx_ws,
    unsigned short* __restrict__ Wt_ws, float* __restrict__ u_ws,
    float* __restrict__ P_ws, float* __restrict__ v_ws)
{
  __shared__ unsigned short As[64 * AS_T];     // ~41.5 KB
  __shared__ __align__(16) float bxs[64][16];  // 4 KB
  __shared__ __align__(16) float us[2][16];
  const int tid  = threadIdx.x;
  const int lane = tid & 63;
  const int l15  = lane & 15;
  const int quad = lane >> 4;
  const int w    = tid >> 6;
  const int t0   = blockIdx.x * 64;
  const int tw   = w * 16;

  // stage Bx tile (contiguous [t][16]) and zero u
  ((float4*)&bxs[0][0])[tid] = ((const float4*)(Bx_ws + (size_t)t0 * DS))[tid];
  if (tid < 32) us[tid >> 4][tid & 15] = 0.f;

  // ---- phase 1: A tile ----
  {
    const bf16x8* xv = (const bf16x8*)(xb + (size_t)(t0 + tw + l15) * 64);
    bf16x8 a0 = xv[quad];
    bf16x8 a1 = xv[quad + 4];
    #pragma unroll 2
    for (int ns = 0; ns < 16; ++ns) {
      const bf16x8* wv = (const bf16x8*)(WAt + (size_t)(ns * 16 + l15) * 64);
      f32x4 acc = {0.f, 0.f, 0.f, 0.f};
      acc = __builtin_amdgcn_mfma_f32_16x16x32_bf16(a0, wv[quad],     acc, 0, 0, 0);
      acc = __builtin_amdgcn_mfma_f32_16x16x32_bf16(a1, wv[quad + 4], acc, 0, 0, 0);
      const float bias = bA[ns * 16 + l15];
      #pragma unroll
      for (int r = 0; r < 4; ++r)
        As[(tw + quad * 4 + r) * AS_T + ns * AS_I + l15] = f2bf(acc[r] + bias);
    }
  }
  __syncthreads();

  // ---- phase 2: chunk scan (waves 0,1) ----
  if (w < 2) {
    const int tb = w * 32;
    bf16x8 wb;          // W in B-operand layout: wb[j] = W[quad*8+j][l15]
    #pragma unroll
    for (int j = 0; j < 8; ++j) wb[j] = (__bf16)((quad * 8 + j == l15) ? 1.f : 0.f);
    f32x4 d = {0.f, 0.f, 0.f, 0.f};
    const int qq = quad & 1;

    #pragma unroll 1
    for (int t = 0; t < CHUNK; ++t) {
      const int tl = tb + t;
      const unsigned short* rp = &As[tl * AS_T + l15 * AS_I];
      uint2 r0 = *(const uint2*)(rp);        // k 0..3
      uint2 r1 = *(const uint2*)(rp + 4);    // k 4..7
      uint2 r2 = *(const uint2*)(rp + 8);    // k 8..11
      uint2 r3 = *(const uint2*)(rp + 12);   // k 12..15

      // A-frag (m=l15, k=quad*8+j): quads 0,1 take halves; 2,3 zero
      uint4 abits;
      if (quad == 0)      abits = make_uint4(r0.x, r0.y, r1.x, r1.y);
      else if (quad == 1) abits = make_uint4(r2.x, r2.y, r3.x, r3.y);
      else                abits = make_uint4(0u, 0u, 0u, 0u);
      bf16x8 af = *(bf16x8*)&abits;

      f32x4 z4 = {0.f, 0.f, 0.f, 0.f};
      d = __builtin_amdgcn_mfma_f32_16x16x32_bf16(af, wb, z4, 0, 0, 0);

      // u-update in fp32 (row l15 of A_t)
      float nu = bxs[tl][l15];
      {
        float4 U0 = *(const float4*)&us[w][0];
        float4 U1 = *(const float4*)&us[w][4];
        float4 U2 = *(const float4*)&us[w][8];
        float4 U3 = *(const float4*)&us[w][12];
        nu = fmaf(bflo(r0.x), U0.x, nu); nu = fmaf(bfhi(r0.x), U0.y, nu);
        nu = fmaf(bflo(r0.y), U0.z, nu); nu = fmaf(bfhi(r0.y), U0.w, nu);
        nu = fmaf(bflo(r1.x), U1.x, nu); nu = fmaf(bfhi(r1.x), U1.y, nu);
        nu = fmaf(bflo(r1.y), U1.z, nu); nu = fmaf(bfhi(r1.y), U1.w, nu);
        nu = fmaf(bflo(r2.x), U2.x, nu); nu = fmaf(bfhi(r2.x), U2.y, nu);
        nu = fmaf(bflo(r2.y), U2.z, nu); nu = fmaf(bfhi(r2.y), U2.w, nu);
        nu = fmaf(bflo(r3.x), U3.x, nu); nu = fmaf(bfhi(r3.x), U3.y, nu);
        nu = fmaf(bflo(r3.y), U3.z, nu); nu = fmaf(bfhi(r3.y), U3.w, nu);
      }

      // C-frag -> next B-frag: nb[j] = D[qq*8+j][l15]
      bf16x8 nb;
      nb[0] = (__bf16)__shfl(d[0], (2 * qq + 0) * 16 + l15, 64);
      nb[1] = (__bf16)__shfl(d[1], (2 * qq + 0) * 16 + l15, 64);
      nb[2] = (__bf16)__shfl(d[2], (2 * qq + 0) * 16 + l15, 64);
      nb[3] = (__bf16)__shfl(d[3], (2 * qq + 0) * 16 + l15, 64);
      nb[4] = (__bf16)__shfl(d[0], (2 * qq + 1) * 16 + l15, 64);
      nb[5] = (__bf16)__shfl(d[1], (2 * qq + 1) * 16 + l15, 64);
      nb[6] = (__bf16)__shfl(d[2], (2 * qq + 1) * 16 + l15, 64);
      nb[7] = (__bf16)__shfl(d[3], (2 * qq + 1) * 16 + l15, 64);
      wb = nb;

      // store u_t; overwrite As[tl] with W_t (same [i][k] layout, bf16)
      if (quad == 0) {
        us[w][l15] = nu;
        u_ws[(size_t)(t0 + tl) * DS + l15] = nu;
      }
      #pragma unroll
      for (int r = 0; r < 4; ++r)
        As[tl * AS_T + (quad * 4 + r) * AS_I + l15] = f2bf(d[r]);
    }

    // chunk epilogue: P = final W (C layout), v = final u
    const int chunk = blockIdx.x * 2 + w;
    #pragma unroll
    for (int r = 0; r < 4; ++r)
      P_ws[(size_t)chunk * 256 + (quad * 4 + r) * 16 + l15] = d[r];
    if (quad == 0) v_ws[(size_t)chunk * DS + l15] = us[w][l15];
  }
  __syncthreads();

  // ---- phase 3: flush W tile (64x256 bf16) coalesced ----
  {
    uint4* Wg = (uint4*)(Wt_ws + (size_t)t0 * 256);
    #pragma unroll 1
    for (int z = 0; z < 8; ++z) {
      const int p4 = z * 256 + tid;          // uint4 index (8 ushorts)
      const int f  = p4 * 8;                 // logical ushort index
      const int t  = f >> 8, i = (f >> 4) & 15, k = f & 15;
      const unsigned short* sp = &As[t * AS_T + i * AS_I + k];
      uint2 lo = *(const uint2*)(sp);
      uint2 hi = *(const uint2*)(sp + 4);
      Wg[p4] = make_uint4(lo.x, lo.y, hi.x, hi.y);
    }
  }
}

// ---------------------------------------------------------------------------
// K3: serial boundary scan across chunks (8 batches x 16 lanes = 128 thr).
// ---------------------------------------------------------------------------
__global__ __launch_bounds__(128) void k3_boundary(
    const float* __restrict__ P_ws, const float* __restrict__ v_ws,
    float* __restrict__ hb_ws)
{
  const int tid = threadIdx.x;
  const int b = tid >> 4;
  const int r = tid & 15;
  float h = 0.f;

  const float4* Pr = (const float4*)&P_ws[(size_t)(b * NCH) * 256 + r * 16];
  float4 c0 = Pr[0], c1 = Pr[1], c2 = Pr[2], c3 = Pr[3];
  float vc = v_ws[(size_t)(b * NCH) * DS + r];

  for (int c = 0; c < NCH; ++c) {
    const int chunk = b * NCH + c;
    float4 n0 = c0, n1 = c1, n2 = c2, n3 = c3; float nv = 0.f;
    if (c < NCH - 1) {
      const float4* Pn = (const float4*)&P_ws[(size_t)(chunk + 1) * 256 + r * 16];
      n0 = Pn[0]; n1 = Pn[1]; n2 = Pn[2]; n3 = Pn[3];
      nv = v_ws[(size_t)(chunk + 1) * DS + r];
    }
    hb_ws[(size_t)chunk * DS + r] = h;
    float acc = vc;
    acc += c0.x*__shfl(h, 0,16) + c0.y*__shfl(h, 1,16) + c0.z*__shfl(h, 2,16) + c0.w*__shfl(h, 3,16);
    acc += c1.x*__shfl(h, 4,16) + c1.y*__shfl(h, 5,16) + c1.z*__shfl(h, 6,16) + c1.w*__shfl(h, 7,16);
    acc += c2.x*__shfl(h, 8,16) + c2.y*__shfl(h, 9,16) + c2.z*__shfl(h,10,16) + c2.w*__shfl(h,11,16);
    acc += c3.x*__shfl(h,12,16) + c3.y*__shfl(h,13,16) + c3.z*__shfl(h,14,16) + c3.w*__shfl(h,15,16);
    h = acc;
    c0 = n0; c1 = n1; c2 = n2; c3 = n3; vc = nv;
  }
}

// ---------------------------------------------------------------------------
// K4new: h_t = W_t * h_entry(chunk) + u_t — fully parallel.
// Thread = (t, i): 16 bf16 row load (coalesced 32B), 16 FMA.
// ---------------------------------------------------------------------------
__global__ __launch_bounds__(256) void k4n(
    const unsigned short* __restrict__ Wt_ws, const float* __restrict__ u_ws,
    const float* __restrict__ hb_ws, float* __restrict__ hs_ws)
{
  const int g = blockIdx.x * 256 + threadIdx.x;
  const int t = g >> 4, i = g & 15;
  const int chunk = t >> 5;                   // CHUNK = 32
  const uint4* wr = (const uint4*)(Wt_ws + (size_t)t * 256 + i * 16);
  uint4 wa = wr[0], wbv = wr[1];
  const float4* hp = (const float4*)(hb_ws + (size_t)chunk * DS);
  float4 h0 = hp[0], h1 = hp[1], h2 = hp[2], h3 = hp[3];
  float acc = u_ws[(size_t)t * DS + i];
  acc = fmaf(bflo(wa.x),  h0.x, acc); acc = fmaf(bfhi(wa.x),  h0.y, acc);
  acc = fmaf(bflo(wa.y),  h0.z, acc); acc = fmaf(bfhi(wa.y),  h0.w, acc);
  acc = fmaf(bflo(wa.z),  h1.x, acc); acc = fmaf(bfhi(wa.z),  h1.y, acc);
  acc = fmaf(bflo(wa.w),  h1.z, acc); acc = fmaf(bfhi(wa.w),  h1.w, acc);
  acc = fmaf(bflo(wbv.x), h2.x, acc); acc = fmaf(bfhi(wbv.x), h2.y, acc);
  acc = fmaf(bflo(wbv.y), h2.z, acc); acc = fmaf(bfhi(wbv.y), h2.w, acc);
  acc = fmaf(bflo(wbv.z), h3.x, acc); acc = fmaf(bfhi(wbv.z), h3.y, acc);
  acc = fmaf(bflo(wbv.w), h3.z, acc); acc = fmaf(bfhi(wbv.w), h3.w, acc);
  hs_ws[(size_t)t * DS + i] = acc;
}

// ---------------------------------------------------------------------------
// GEMM-C fused: z = x@WC + bC (never stored); out[t][d] = sum_n z[t,n,d]*h[t,n].
// ---------------------------------------------------------------------------
__global__ __launch_bounds__(256) void g_C(
    const unsigned short* __restrict__ xb, const unsigned short* __restrict__ WCt,
    const float* __restrict__ bC, const float* __restrict__ hs_ws,
    float* __restrict__ out)
{
  __shared__ float hsh[64][17];
  __shared__ float bCs[1024];
  const int tid  = threadIdx.x;
  const int lane = tid & 63;
  const int l15  = lane & 15;
  const int quad = lane >> 4;
  const int w    = tid >> 6;
  const int t0   = blockIdx.x * 64;
  const int tw   = t0 + w * 16;

  {
    float4 hv = ((const float4*)(hs_ws + (size_t)t0 * DS))[tid];
    const int t = tid >> 2, n0 = (tid & 3) * 4;
    hsh[t][n0] = hv.x; hsh[t][n0+1] = hv.y; hsh[t][n0+2] = hv.z; hsh[t][n0+3] = hv.w;
    ((float4*)bCs)[tid] = ((const float4*)bC)[tid];
  }

  const bf16x8* xv = (const bf16x8*)(xb + (size_t)(tw + l15) * 64);
  bf16x8 a0 = xv[quad];
  bf16x8 a1 = xv[quad + 4];
  __syncthreads();

  f32x4 ota[4];
  #pragma unroll
  for (int r = 0; r < 4; ++r) ota[r] = (f32x4){0.f, 0.f, 0.f, 0.f};

  #pragma unroll 2
  for (int n = 0; n < 16; ++n) {
    f32x4 ac[4];
    #pragma unroll
    for (int r = 0; r < 4; ++r) {
      const bf16x8* wv = (const bf16x8*)(WCt + (size_t)((n * 4 + r) * 16 + l15) * 64);
      f32x4 t = {0.f, 0.f, 0.f, 0.f};
      t = __builtin_amdgcn_mfma_f32_16x16x32_bf16(a0, wv[quad],     t, 0, 0, 0);
      t = __builtin_amdgcn_mfma_f32_16x16x32_bf16(a1, wv[quad + 4], t, 0, 0, 0);
      ac[r] = t;
    }
    float hn[4];
    #pragma unroll
    for (int reg = 0; reg < 4; ++reg) hn[reg] = hsh[w * 16 + quad * 4 + reg][n];
    #pragma unroll
    for (int r = 0; r < 4; ++r) {
      const float bc = bCs[n * 64 + r * 16 + l15];
      #pragma unroll
      for (int reg = 0; reg < 4; ++reg)
        ota[r][reg] = fmaf(ac[r][reg] + bc, hn[reg], ota[r][reg]);
    }
  }

  #pragma unroll
  for (int r = 0; r < 4; ++r)
    #pragma unroll
    for (int reg = 0; reg < 4; ++reg)
      out[(size_t)(tw + quad * 4 + reg) * DM + r * 16 + l15] = ota[r][reg];
}

// ---------------------------------------------------------------------------
extern "C" void kernel_launch(void* const* d_in, const int* in_sizes, int n_in,
                              void* d_out, int out_size, void* d_ws, size_t ws_size,
                              hipStream_t stream) {
  const float* x  = (const float*)d_in[0];
  const float* WA = (const float*)d_in[1];
  const float* bA = (const float*)d_in[2];
  const float* WB = (const float*)d_in[3];
  const float* bB = (const float*)d_in[4];
  const float* WC = (const float*)d_in[5];
  const float* bC = (const float*)d_in[6];
  float* out = (float*)d_out;

  float* ws    = (float*)d_ws;
  float* Bx_ws = ws;                              // BS*16
  float* P_ws  = Bx_ws + (size_t)BS * DS;         // NCH_TOT*256
  float* v_ws  = P_ws  + (size_t)NCH_TOT * 256;   // NCH_TOT*16
  float* hb_ws = v_ws  + (size_t)NCH_TOT * DS;    // NCH_TOT*16
  float* hs_ws = hb_ws + (size_t)NCH_TOT * DS;    // BS*16
  float* u_ws  = hs_ws + (size_t)BS * DS;         // BS*16
  unsigned short* xb    = (unsigned short*)(u_ws + (size_t)BS * DS); // BS*64
  unsigned short* WAt   = xb  + (size_t)BS * 64;  // 16384
  unsigned short* WBt   = WAt + 256 * 64;         // 65536
  unsigned short* WCt   = WBt + 1024 * 64;        // 65536
  unsigned short* Wt_ws = WCt + 1024 * 64;        // BS*256 (16.8 MB)

  k0_cast    <<<1600,      256, 0, stream>>>(x, WA, WB, WC, xb, WAt, WBt, WCt);
  g_B        <<<BS / 64,   256, 0, stream>>>(xb, WBt, bB, x, Bx_ws);
  gk2        <<<BS / 64,   256, 0, stream>>>(xb, WAt, bA, Bx_ws, Wt_ws, u_ws, P_ws, v_ws);
  k3_boundary<<<1,         128, 0, stream>>>(P_ws, v_ws, hb_ws);
  k4n        <<<BS * 16 / 256, 256, 0, stream>>>(Wt_ws, u_ws, hb_ws, hs_ws);
  g_C        <<<BS / 64,   256, 0, stream>>>(xb, WCt, bC, hs_ws, out);
}

// Round 9
// 185.622 us; speedup vs baseline: 2.8468x; 1.1442x over previous
//
#include <hip/hip_runtime.h>

// Problem constants (B=8, S=4096, D=64, ds=16)
#define BATCH   8
#define SEQ     4096
#define DM      64
#define DS      16
#define BS      (BATCH*SEQ)      // 32768 timesteps
#define CHUNK   32               // scan chunk length
#define NCH     (SEQ/CHUNK)      // 128 chunks per batch
#define NCH_TOT (BATCH*NCH)      // 1024 chunks total
#define SG      16               // chunks per supergroup
#define NSG     (NCH_TOT/SG)     // 64 supergroups (8 per batch)

typedef __attribute__((ext_vector_type(8))) __bf16 bf16x8;
typedef __attribute__((ext_vector_type(4))) float  f32x4;

__device__ __forceinline__ unsigned short f2bf(float f) {
  unsigned int u = __float_as_uint(f);
  u += 0x7fffu + ((u >> 16) & 1u);          // RNE (finite values)
  return (unsigned short)(u >> 16);
}
__device__ __forceinline__ float bflo(unsigned int u) { return __uint_as_float(u << 16); }
__device__ __forceinline__ float bfhi(unsigned int u) { return __uint_as_float(u & 0xffff0000u); }

// LDS A-tile strides (ushorts): b64-aligned rows, bank-spread
#define AS_I 20                 // per-i stride (40 B)
#define AS_T 324                // per-t stride (648 B; 16*20+4 pad)

// ---------------------------------------------------------------------------
// K0: cast x -> bf16 (blocks 0..1023) and transpose+cast weights.
// ---------------------------------------------------------------------------
__global__ __launch_bounds__(256) void k0_cast(
    const float* __restrict__ x, const float* __restrict__ WA,
    const float* __restrict__ WB, const float* __restrict__ WC,
    unsigned short* __restrict__ xb, unsigned short* __restrict__ WAt,
    unsigned short* __restrict__ WBt, unsigned short* __restrict__ WCt)
{
  const int b = blockIdx.x;
  if (b < 1024) {
    const int i = (b * 256 + threadIdx.x) * 8;
    float4 v0 = *(const float4*)(x + i);
    float4 v1 = *(const float4*)(x + i + 4);
    ushort4 o0 = {f2bf(v0.x), f2bf(v0.y), f2bf(v0.z), f2bf(v0.w)};
    ushort4 o1 = {f2bf(v1.x), f2bf(v1.y), f2bf(v1.z), f2bf(v1.w)};
    *(ushort4*)(xb + i)     = o0;
    *(ushort4*)(xb + i + 4) = o1;
  } else {
    const int o = (b - 1024) * 256 + threadIdx.x;
    if (o < 16384) {
      const int c = o >> 6, e = o & 63;
      WAt[o] = f2bf(WA[e * 256 + c]);
    } else if (o < 16384 + 65536) {
      const int p = o - 16384;
      const int c = p >> 6, e = p & 63;
      WBt[p] = f2bf(WB[e * 1024 + c]);
    } else {
      const int p = o - 16384 - 65536;
      const int c = p >> 6, e = p & 63;
      WCt[p] = f2bf(WC[e * 1024 + c]);
    }
  }
}

// ---------------------------------------------------------------------------
// G1 = g_B + gk2 fused.  Per block: 64 t = 2 chunks.
//  B-phase: Bx[t][n] via MFMA + fp32 epilogue -> LDS bxs (no global trip).
//  A-phase: A-tile via MFMA -> LDS bf16 As.
//  scan   : waves 0,1 run 32-step chunk recurrence on matrix cores
//           (C-frag -> B-frag via 8 shuffles); writes u_t and W_t prefixes.
//  flush  : W tile -> global (bf16).
// LDS: As (41.5 KB) time-shared with xs+bBs; + bxs 4 KB + us.
// ---------------------------------------------------------------------------
__global__ __launch_bounds__(256) void g1(
    const unsigned short* __restrict__ xb, const unsigned short* __restrict__ WBt,
    const float* __restrict__ bB, const float* __restrict__ x,
    const unsigned short* __restrict__ WAt, const float* __restrict__ bA,
    unsigned short* __restrict__ Wt_ws, float* __restrict__ u_ws,
    float* __restrict__ P_ws, float* __restrict__ v_ws)
{
  __shared__ __align__(16) unsigned char smem[64 * AS_T * 2];   // 41472 B
  float (*xs)[68]     = (float (*)[68])smem;                    // 17408 B
  float* bBs          = (float*)(smem + 17408);                 //  4096 B
  unsigned short* As  = (unsigned short*)smem;
  __shared__ __align__(16) float bxs[64][16];
  __shared__ __align__(16) float us[2][16];

  const int tid  = threadIdx.x;
  const int lane = tid & 63;
  const int l15  = lane & 15;
  const int quad = lane >> 4;
  const int w    = tid >> 6;
  const int t0   = blockIdx.x * 64;
  const int twl  = w * 16;               // local t base of this wave

  { // stage fp32 x tile + bB; zero u
    const float4* xg = (const float4*)(x + (size_t)t0 * DM);
    #pragma unroll
    for (int i = 0; i < 4; ++i) {
      const int f4 = tid + 256 * i;
      ((float4*)&xs[f4 >> 4][0])[f4 & 15] = xg[f4];
    }
    ((float4*)bBs)[tid] = ((const float4*)bB)[tid];
    if (tid < 32) us[tid >> 4][tid & 15] = 0.f;
  }

  // A-operand frags (shared by both GEMMs)
  const bf16x8* xv = (const bf16x8*)(xb + (size_t)(t0 + twl + l15) * 64);
  bf16x8 a0 = xv[quad];
  bf16x8 a1 = xv[quad + 4];
  __syncthreads();

  // ---- B-phase: Bx -> bxs ----
  #pragma unroll 2
  for (int n = 0; n < 16; ++n) {
    f32x4 ac[4];
    #pragma unroll
    for (int r = 0; r < 4; ++r) {
      const bf16x8* wv = (const bf16x8*)(WBt + (size_t)((n * 4 + r) * 16 + l15) * 64);
      f32x4 t = {0.f, 0.f, 0.f, 0.f};
      t = __builtin_amdgcn_mfma_f32_16x16x32_bf16(a0, wv[quad],     t, 0, 0, 0);
      t = __builtin_amdgcn_mfma_f32_16x16x32_bf16(a1, wv[quad + 4], t, 0, 0, 0);
      ac[r] = t;
    }
    float part[4] = {0.f, 0.f, 0.f, 0.f};
    #pragma unroll
    for (int r = 0; r < 4; ++r) {
      const float bb = bBs[n * 64 + r * 16 + l15];
      #pragma unroll
      for (int reg = 0; reg < 4; ++reg) {
        const int tl = twl + quad * 4 + reg;
        part[reg] = fmaf(ac[r][reg] + bb, xs[tl][r * 16 + l15], part[reg]);
      }
    }
    #pragma unroll
    for (int off = 1; off < 16; off <<= 1) {
      #pragma unroll
      for (int reg = 0; reg < 4; ++reg)
        part[reg] += __shfl_xor(part[reg], off, 64);
    }
    if (l15 == 0) {
      #pragma unroll
      for (int reg = 0; reg < 4; ++reg)
        bxs[twl + quad * 4 + reg][n] = part[reg];
    }
  }
  __syncthreads();   // bxs ready; xs/bBs dead

  // ---- A-phase: A tile into As ----
  #pragma unroll 2
  for (int ns = 0; ns < 16; ++ns) {
    const bf16x8* wv = (const bf16x8*)(WAt + (size_t)(ns * 16 + l15) * 64);
    f32x4 acc = {0.f, 0.f, 0.f, 0.f};
    acc = __builtin_amdgcn_mfma_f32_16x16x32_bf16(a0, wv[quad],     acc, 0, 0, 0);
    acc = __builtin_amdgcn_mfma_f32_16x16x32_bf16(a1, wv[quad + 4], acc, 0, 0, 0);
    const float bias = bA[ns * 16 + l15];
    #pragma unroll
    for (int r = 0; r < 4; ++r)
      As[(twl + quad * 4 + r) * AS_T + ns * AS_I + l15] = f2bf(acc[r] + bias);
  }
  __syncthreads();

  // ---- scan (waves 0,1) ----
  if (w < 2) {
    const int tb = w * 32;
    bf16x8 wb;          // W in B-operand layout: wb[j] = W[quad*8+j][l15]
    #pragma unroll
    for (int j = 0; j < 8; ++j) wb[j] = (__bf16)((quad * 8 + j == l15) ? 1.f : 0.f);
    f32x4 d = {0.f, 0.f, 0.f, 0.f};
    const int qq = quad & 1;

    #pragma unroll 1
    for (int t = 0; t < CHUNK; ++t) {
      const int tl = tb + t;
      const unsigned short* rp = &As[tl * AS_T + l15 * AS_I];
      uint2 r0 = *(const uint2*)(rp);        // k 0..3
      uint2 r1 = *(const uint2*)(rp + 4);    // k 4..7
      uint2 r2 = *(const uint2*)(rp + 8);    // k 8..11
      uint2 r3 = *(const uint2*)(rp + 12);   // k 12..15

      uint4 abits;
      if (quad == 0)      abits = make_uint4(r0.x, r0.y, r1.x, r1.y);
      else if (quad == 1) abits = make_uint4(r2.x, r2.y, r3.x, r3.y);
      else                abits = make_uint4(0u, 0u, 0u, 0u);
      bf16x8 af = *(bf16x8*)&abits;

      f32x4 z4 = {0.f, 0.f, 0.f, 0.f};
      d = __builtin_amdgcn_mfma_f32_16x16x32_bf16(af, wb, z4, 0, 0, 0);

      float nu = bxs[tl][l15];
      {
        float4 U0 = *(const float4*)&us[w][0];
        float4 U1 = *(const float4*)&us[w][4];
        float4 U2 = *(const float4*)&us[w][8];
        float4 U3 = *(const float4*)&us[w][12];
        nu = fmaf(bflo(r0.x), U0.x, nu); nu = fmaf(bfhi(r0.x), U0.y, nu);
        nu = fmaf(bflo(r0.y), U0.z, nu); nu = fmaf(bfhi(r0.y), U0.w, nu);
        nu = fmaf(bflo(r1.x), U1.x, nu); nu = fmaf(bfhi(r1.x), U1.y, nu);
        nu = fmaf(bflo(r2.x), U2.x, nu); nu = fmaf(bfhi(r2.x), U2.y, nu);
        nu = fmaf(bflo(r2.y), U2.z, nu); nu = fmaf(bfhi(r2.y), U2.w, nu);
        nu = fmaf(bflo(r3.x), U3.x, nu); nu = fmaf(bfhi(r3.x), U3.y, nu);
        nu = fmaf(bflo(r1.y), U1.z, nu); nu = fmaf(bfhi(r1.y), U1.w, nu);
        nu = fmaf(bflo(r3.y), U3.z, nu); nu = fmaf(bfhi(r3.y), U3.w, nu);
      }

      bf16x8 nb;
      nb[0] = (__bf16)__shfl(d[0], (2 * qq + 0) * 16 + l15, 64);
      nb[1] = (__bf16)__shfl(d[1], (2 * qq + 0) * 16 + l15, 64);
      nb[2] = (__bf16)__shfl(d[2], (2 * qq + 0) * 16 + l15, 64);
      nb[3] = (__bf16)__shfl(d[3], (2 * qq + 0) * 16 + l15, 64);
      nb[4] = (__bf16)__shfl(d[0], (2 * qq + 1) * 16 + l15, 64);
      nb[5] = (__bf16)__shfl(d[1], (2 * qq + 1) * 16 + l15, 64);
      nb[6] = (__bf16)__shfl(d[2], (2 * qq + 1) * 16 + l15, 64);
      nb[7] = (__bf16)__shfl(d[3], (2 * qq + 1) * 16 + l15, 64);
      wb = nb;

      if (quad == 0) {
        us[w][l15] = nu;
        u_ws[(size_t)(t0 + tl) * DS + l15] = nu;
      }
      #pragma unroll
      for (int r = 0; r < 4; ++r)
        As[tl * AS_T + (quad * 4 + r) * AS_I + l15] = f2bf(d[r]);
    }

    const int chunk = blockIdx.x * 2 + w;
    #pragma unroll
    for (int r = 0; r < 4; ++r)
      P_ws[(size_t)chunk * 256 + (quad * 4 + r) * 16 + l15] = d[r];
    if (quad == 0) v_ws[(size_t)chunk * DS + l15] = us[w][l15];
  }
  __syncthreads();

  // ---- flush W tile (64x256 bf16) coalesced ----
  {
    uint4* Wg = (uint4*)(Wt_ws + (size_t)t0 * 256);
    #pragma unroll 1
    for (int z = 0; z < 8; ++z) {
      const int p4 = z * 256 + tid;
      const int f  = p4 * 8;
      const int t  = f >> 8, i = (f >> 4) & 15, k = f & 15;
      const unsigned short* sp = &As[t * AS_T + i * AS_I + k];
      uint2 lo = *(const uint2*)(sp);
      uint2 hi = *(const uint2*)(sp + 4);
      Wg[p4] = make_uint4(lo.x, lo.y, hi.x, hi.y);
    }
  }
}

// ---------------------------------------------------------------------------
// K3a: supergroup fold.  One wave per supergroup s (64 total): serially
// compose 16 chunk transitions with MFMA: (Q,w) <- (P_c Q, P_c w + v_c).
// ---------------------------------------------------------------------------
__global__ __launch_bounds__(256) void k3a(
    const float* __restrict__ P_ws, const float* __restrict__ v_ws,
    float* __restrict__ Q_ws, float* __restrict__ w_ws)
{
  __shared__ float wsv[4][16];
  const int tid  = threadIdx.x;
  const int lane = tid & 63;
  const int l15  = lane & 15;
  const int quad = lane >> 4;
  const int wv   = tid >> 6;
  const int s    = blockIdx.x * 4 + wv;
  const int qq   = quad & 1;

  if (lane < 16) wsv[wv][lane] = 0.f;
  bf16x8 wb;
  #pragma unroll
  for (int j = 0; j < 8; ++j) wb[j] = (__bf16)((quad * 8 + j == l15) ? 1.f : 0.f);
  f32x4 d = {0.f, 0.f, 0.f, 0.f};

  #pragma unroll 1
  for (int t = 0; t < SG; ++t) {
    const int chunk = s * SG + t;
    float4 p0 = {0.f,0.f,0.f,0.f}, p1 = {0.f,0.f,0.f,0.f};
    if (quad < 2) {
      const float4* pr = (const float4*)(P_ws + (size_t)chunk * 256 + l15 * 16 + quad * 8);
      p0 = pr[0]; p1 = pr[1];
    }
    bf16x8 af;
    af[0] = (__bf16)p0.x; af[1] = (__bf16)p0.y; af[2] = (__bf16)p0.z; af[3] = (__bf16)p0.w;
    af[4] = (__bf16)p1.x; af[5] = (__bf16)p1.y; af[6] = (__bf16)p1.z; af[7] = (__bf16)p1.w;

    f32x4 z4 = {0.f, 0.f, 0.f, 0.f};
    d = __builtin_amdgcn_mfma_f32_16x16x32_bf16(af, wb, z4, 0, 0, 0);

    // w update (fp32, exact P rows)
    float part = 0.f;
    if (quad < 2) {
      const float* wrow = &wsv[wv][quad * 8];
      part = p0.x*wrow[0] + p0.y*wrow[1] + p0.z*wrow[2] + p0.w*wrow[3]
           + p1.x*wrow[4] + p1.y*wrow[5] + p1.z*wrow[6] + p1.w*wrow[7];
    }
    part += __shfl_xor(part, 16, 64);
    const float nv = v_ws[(size_t)chunk * DS + l15];

    bf16x8 nb;
    nb[0] = (__bf16)__shfl(d[0], (2 * qq + 0) * 16 + l15, 64);
    nb[1] = (__bf16)__shfl(d[1], (2 * qq + 0) * 16 + l15, 64);
    nb[2] = (__bf16)__shfl(d[2], (2 * qq + 0) * 16 + l15, 64);
    nb[3] = (__bf16)__shfl(d[3], (2 * qq + 0) * 16 + l15, 64);
    nb[4] = (__bf16)__shfl(d[0], (2 * qq + 1) * 16 + l15, 64);
    nb[5] = (__bf16)__shfl(d[1], (2 * qq + 1) * 16 + l15, 64);
    nb[6] = (__bf16)__shfl(d[2], (2 * qq + 1) * 16 + l15, 64);
    nb[7] = (__bf16)__shfl(d[3], (2 * qq + 1) * 16 + l15, 64);
    wb = nb;

    if (quad == 0) wsv[wv][l15] = part + nv;
  }

  #pragma unroll
  for (int r = 0; r < 4; ++r)
    Q_ws[(size_t)s * 256 + (quad * 4 + r) * 16 + l15] = d[r];
  if (quad == 0) w_ws[(size_t)s * DS + l15] = wsv[wv][l15];
}

// ---------------------------------------------------------------------------
// K3b: serial scan over 8 supergroups per batch (8 b x 16 lanes = 128 thr).
// Writes the ENTERING state of every supergroup.
// ---------------------------------------------------------------------------
__global__ __launch_bounds__(128) void k3b(
    const float* __restrict__ Q_ws, const float* __restrict__ w_ws,
    float* __restrict__ hbg_ws)
{
  const int tid = threadIdx.x;
  const int b = tid >> 4;
  const int r = tid & 15;
  float h = 0.f;

  #pragma unroll 1
  for (int g = 0; g < 8; ++g) {
    const int s = b * 8 + g;
    const float4* Pr = (const float4*)&Q_ws[(size_t)s * 256 + r * 16];
    float4 c0 = Pr[0], c1 = Pr[1], c2 = Pr[2], c3 = Pr[3];
    const float vc = w_ws[(size_t)s * DS + r];
    hbg_ws[(size_t)s * DS + r] = h;
    float acc = vc;
    acc += c0.x*__shfl(h, 0,16) + c0.y*__shfl(h, 1,16) + c0.z*__shfl(h, 2,16) + c0.w*__shfl(h, 3,16);
    acc += c1.x*__shfl(h, 4,16) + c1.y*__shfl(h, 5,16) + c1.z*__shfl(h, 6,16) + c1.w*__shfl(h, 7,16);
    acc += c2.x*__shfl(h, 8,16) + c2.y*__shfl(h, 9,16) + c2.z*__shfl(h,10,16) + c2.w*__shfl(h,11,16);
    acc += c3.x*__shfl(h,12,16) + c3.y*__shfl(h,13,16) + c3.z*__shfl(h,14,16) + c3.w*__shfl(h,15,16);
    h = acc;
  }
}

// ---------------------------------------------------------------------------
// K3c: within-supergroup replay: entering state of each chunk.  64 groups
// x 16 lanes, serial over 16 chunks.  4 blocks x 256 thr.
// ---------------------------------------------------------------------------
__global__ __launch_bounds__(256) void k3c(
    const float* __restrict__ P_ws, const float* __restrict__ v_ws,
    const float* __restrict__ hbg_ws, float* __restrict__ hb_ws)
{
  const int tid = threadIdx.x;
  const int s = blockIdx.x * 16 + (tid >> 4);
  const int r = tid & 15;
  float h = hbg_ws[(size_t)s * DS + r];

  #pragma unroll 1
  for (int t = 0; t < SG; ++t) {
    const int chunk = s * SG + t;
    const float4* Pr = (const float4*)&P_ws[(size_t)chunk * 256 + r * 16];
    float4 c0 = Pr[0], c1 = Pr[1], c2 = Pr[2], c3 = Pr[3];
    const float vc = v_ws[(size_t)chunk * DS + r];
    hb_ws[(size_t)chunk * DS + r] = h;
    float acc = vc;
    acc += c0.x*__shfl(h, 0,16) + c0.y*__shfl(h, 1,16) + c0.z*__shfl(h, 2,16) + c0.w*__shfl(h, 3,16);
    acc += c1.x*__shfl(h, 4,16) + c1.y*__shfl(h, 5,16) + c1.z*__shfl(h, 6,16) + c1.w*__shfl(h, 7,16);
    acc += c2.x*__shfl(h, 8,16) + c2.y*__shfl(h, 9,16) + c2.z*__shfl(h,10,16) + c2.w*__shfl(h,11,16);
    acc += c3.x*__shfl(h,12,16) + c3.y*__shfl(h,13,16) + c3.z*__shfl(h,14,16) + c3.w*__shfl(h,15,16);
    h = acc;
  }
}

// ---------------------------------------------------------------------------
// G2 = k4n + g_C fused.  Per block: 64 t.  Phase 1: hs = W_t h_entry + u_t
// into LDS.  Phase 2: out = sum_n (x@WC + bC)[n,d] * hs[n] via MFMA.
// ---------------------------------------------------------------------------
__global__ __launch_bounds__(256) void g2(
    const unsigned short* __restrict__ xb, const unsigned short* __restrict__ WCt,
    const float* __restrict__ bC, const unsigned short* __restrict__ Wt_ws,
    const float* __restrict__ u_ws, const float* __restrict__ hb_ws,
    float* __restrict__ out)
{
  __shared__ float hsh[64][17];
  __shared__ float bCs[1024];
  const int tid  = threadIdx.x;
  const int lane = tid & 63;
  const int l15  = lane & 15;
  const int quad = lane >> 4;
  const int w    = tid >> 6;
  const int t0   = blockIdx.x * 64;
  const int twl  = w * 16;

  ((float4*)bCs)[tid] = ((const float4*)bC)[tid];

  // phase 1: hs for the 64 t of this block (4 (t,i) cells per thread)
  #pragma unroll
  for (int z = 0; z < 4; ++z) {
    const int gcell = z * 256 + tid;
    const int tl = gcell >> 4, i = gcell & 15;
    const int t = t0 + tl;
    const uint4* wr = (const uint4*)(Wt_ws + (size_t)t * 256 + i * 16);
    uint4 wa = wr[0], wbv = wr[1];
    const float4* hp = (const float4*)(hb_ws + (size_t)(t >> 5) * DS);
    float4 h0 = hp[0], h1 = hp[1], h2 = hp[2], h3 = hp[3];
    float acc = u_ws[(size_t)t * DS + i];
    acc = fmaf(bflo(wa.x),  h0.x, acc); acc = fmaf(bfhi(wa.x),  h0.y, acc);
    acc = fmaf(bflo(wa.y),  h0.z, acc); acc = fmaf(bfhi(wa.y),  h0.w, acc);
    acc = fmaf(bflo(wa.z),  h1.x, acc); acc = fmaf(bfhi(wa.z),  h1.y, acc);
    acc = fmaf(bflo(wa.w),  h1.z, acc); acc = fmaf(bfhi(wa.w),  h1.w, acc);
    acc = fmaf(bflo(wbv.x), h2.x, acc); acc = fmaf(bfhi(wbv.x), h2.y, acc);
    acc = fmaf(bflo(wbv.y), h2.z, acc); acc = fmaf(bfhi(wbv.y), h2.w, acc);
    acc = fmaf(bflo(wbv.z), h3.x, acc); acc = fmaf(bfhi(wbv.z), h3.y, acc);
    acc = fmaf(bflo(wbv.w), h3.z, acc); acc = fmaf(bfhi(wbv.w), h3.w, acc);
    hsh[tl][i] = acc;
  }

  const bf16x8* xv = (const bf16x8*)(xb + (size_t)(t0 + twl + l15) * 64);
  bf16x8 a0 = xv[quad];
  bf16x8 a1 = xv[quad + 4];
  __syncthreads();

  f32x4 ota[4];
  #pragma unroll
  for (int r = 0; r < 4; ++r) ota[r] = (f32x4){0.f, 0.f, 0.f, 0.f};

  #pragma unroll 2
  for (int n = 0; n < 16; ++n) {
    f32x4 ac[4];
    #pragma unroll
    for (int r = 0; r < 4; ++r) {
      const bf16x8* wv = (const bf16x8*)(WCt + (size_t)((n * 4 + r) * 16 + l15) * 64);
      f32x4 t = {0.f, 0.f, 0.f, 0.f};
      t = __builtin_amdgcn_mfma_f32_16x16x32_bf16(a0, wv[quad],     t, 0, 0, 0);
      t = __builtin_amdgcn_mfma_f32_16x16x32_bf16(a1, wv[quad + 4], t, 0, 0, 0);
      ac[r] = t;
    }
    float hn[4];
    #pragma unroll
    for (int reg = 0; reg < 4; ++reg) hn[reg] = hsh[twl + quad * 4 + reg][n];
    #pragma unroll
    for (int r = 0; r < 4; ++r) {
      const float bc = bCs[n * 64 + r * 16 + l15];
      #pragma unroll
      for (int reg = 0; reg < 4; ++reg)
        ota[r][reg] = fmaf(ac[r][reg] + bc, hn[reg], ota[r][reg]);
    }
  }

  #pragma unroll
  for (int r = 0; r < 4; ++r)
    #pragma unroll
    for (int reg = 0; reg < 4; ++reg)
      out[(size_t)(t0 + twl + quad * 4 + reg) * DM + r * 16 + l15] = ota[r][reg];
}

// ---------------------------------------------------------------------------
extern "C" void kernel_launch(void* const* d_in, const int* in_sizes, int n_in,
                              void* d_out, int out_size, void* d_ws, size_t ws_size,
                              hipStream_t stream) {
  const float* x  = (const float*)d_in[0];
  const float* WA = (const float*)d_in[1];
  const float* bA = (const float*)d_in[2];
  const float* WB = (const float*)d_in[3];
  const float* bB = (const float*)d_in[4];
  const float* WC = (const float*)d_in[5];
  const float* bC = (const float*)d_in[6];
  float* out = (float*)d_out;

  float* ws     = (float*)d_ws;
  float* P_ws   = ws;                               // NCH_TOT*256
  float* v_ws   = P_ws   + (size_t)NCH_TOT * 256;   // NCH_TOT*16
  float* u_ws   = v_ws   + (size_t)NCH_TOT * DS;    // BS*16
  float* Q_ws   = u_ws   + (size_t)BS * DS;         // NSG*256
  float* w_ws   = Q_ws   + (size_t)NSG * 256;       // NSG*16
  float* hbg_ws = w_ws   + (size_t)NSG * DS;        // NSG*16
  float* hb_ws  = hbg_ws + (size_t)NSG * DS;        // NCH_TOT*16
  unsigned short* xb    = (unsigned short*)(hb_ws + (size_t)NCH_TOT * DS);
  unsigned short* WAt   = xb  + (size_t)BS * 64;    // 16384
  unsigned short* WBt   = WAt + 256 * 64;           // 65536
  unsigned short* WCt   = WBt + 1024 * 64;          // 65536
  unsigned short* Wt_ws = WCt + 1024 * 64;          // BS*256

  k0_cast <<<1600,    256, 0, stream>>>(x, WA, WB, WC, xb, WAt, WBt, WCt);
  g1      <<<BS / 64, 256, 0, stream>>>(xb, WBt, bB, x, WAt, bA, Wt_ws, u_ws, P_ws, v_ws);
  k3a     <<<NSG / 4, 256, 0, stream>>>(P_ws, v_ws, Q_ws, w_ws);
  k3b     <<<1,       128, 0, stream>>>(Q_ws, w_ws, hbg_ws);
  k3c     <<<4,       256, 0, stream>>>(P_ws, v_ws, hbg_ws, hb_ws);
  g2      <<<BS / 64, 256, 0, stream>>>(xb, WCt, bC, Wt_ws, u_ws, hb_ws, out);
}

// Round 10
// 181.819 us; speedup vs baseline: 2.9064x; 1.0209x over previous
//
#include <hip/hip_runtime.h>

// Problem constants (B=8, S=4096, D=64, ds=16)
#define BATCH   8
#define SEQ     4096
#define DM      64
#define DS      16
#define BS      (BATCH*SEQ)      // 32768 timesteps
#define CHUNK   16               // scan chunk length
#define NCHT    (BS/CHUNK)       // 2048 chunks total (256 per batch)
#define SG      16               // chunks per supergroup
#define NSG     (NCHT/SG)        // 128 supergroups (16 per batch)

typedef __attribute__((ext_vector_type(8))) __bf16 bf16x8;
typedef __attribute__((ext_vector_type(4))) float  f32x4;

__device__ __forceinline__ unsigned short f2bf(float f) {
  unsigned int u = __float_as_uint(f);
  u += 0x7fffu + ((u >> 16) & 1u);          // RNE (finite values)
  return (unsigned short)(u >> 16);
}
__device__ __forceinline__ float bflo(unsigned int u) { return __uint_as_float(u << 16); }
__device__ __forceinline__ float bfhi(unsigned int u) { return __uint_as_float(u & 0xffff0000u); }

// LDS A-tile strides (ushorts): per-i 20 (40B), per-t 324 (648B)
#define AS_I 20
#define AS_T 324

// ---------------------------------------------------------------------------
// K0: transpose+cast weights only (x cast moved into g1).  576 blocks.
// ---------------------------------------------------------------------------
__global__ __launch_bounds__(256) void k0_castw(
    const float* __restrict__ WA, const float* __restrict__ WB,
    const float* __restrict__ WC,
    unsigned short* __restrict__ WAt, unsigned short* __restrict__ WBt,
    unsigned short* __restrict__ WCt)
{
  const int o = blockIdx.x * 256 + threadIdx.x;
  if (o < 16384) {
    const int c = o >> 6, e = o & 63;
    WAt[o] = f2bf(WA[e * 256 + c]);
  } else if (o < 16384 + 65536) {
    const int p = o - 16384;
    const int c = p >> 6, e = p & 63;
    WBt[p] = f2bf(WB[e * 1024 + c]);
  } else {
    const int p = o - 16384 - 65536;
    const int c = p >> 6, e = p & 63;
    WCt[p] = f2bf(WC[e * 1024 + c]);
  }
}

// ---------------------------------------------------------------------------
// G1: per block 32 t = 2 chunks, 128 thr (2 waves).
//  stage  : fp32 x tile + bB -> LDS.
//  frags  : A-operand frags built from LDS (in-kernel bf16 cast) + stored
//           to xb for g2.
//  B-phase: Bx via MFMA + fp32 epilogue -> LDS bxs.
//  A-phase: A-tile via MFMA -> LDS bf16 As (aliases dead xs).
//  scan   : BOTH waves run their own 16-step chunk recurrence on matrix
//           cores (C-frag -> B-frag via 8 shuffles); u prefixes overwrite
//           bxs; W_t prefixes overwrite As.
//  flush  : Wt + u coalesced to global; chunk (P,v) stored.
// ---------------------------------------------------------------------------
__global__ __launch_bounds__(128) void g1(
    const float* __restrict__ x, const unsigned short* __restrict__ WBt,
    const float* __restrict__ bB, const unsigned short* __restrict__ WAt,
    const float* __restrict__ bA, unsigned short* __restrict__ xb,
    unsigned short* __restrict__ Wt_ws, float* __restrict__ u_ws,
    float* __restrict__ P_ws, float* __restrict__ v_ws)
{
  __shared__ __align__(16) unsigned char smem[32 * AS_T * 2];   // 20736 B
  float (*xs)[68]     = (float (*)[68])smem;                    //  8704 B
  float* bBs          = (float*)(smem + 8704);                  //  4096 B
  unsigned short* As  = (unsigned short*)smem;
  __shared__ __align__(16) float bxs[32][16];
  __shared__ __align__(16) float us[2][16];

  const int tid  = threadIdx.x;
  const int lane = tid & 63;
  const int l15  = lane & 15;
  const int quad = lane >> 4;
  const int w    = tid >> 6;             // 0,1
  const int t0   = blockIdx.x * 32;
  const int twl  = w * 16;

  { // stage fp32 x tile (32x64 = 512 float4) + bB (256 float4); zero us
    const float4* xg = (const float4*)(x + (size_t)t0 * DM);
    #pragma unroll
    for (int i = 0; i < 4; ++i) {
      const int f4 = tid + 128 * i;
      ((float4*)&xs[f4 >> 4][0])[f4 & 15] = xg[f4];
    }
    ((float4*)bBs)[tid]       = ((const float4*)bB)[tid];
    ((float4*)bBs)[tid + 128] = ((const float4*)bB)[tid + 128];
    if (tid < 32) us[tid >> 4][tid & 15] = 0.f;
  }
  __syncthreads();

  // ---- build A-operand frags from LDS; store to xb for g2 ----
  bf16x8 a0, a1;
  {
    const int row = twl + l15;
    union { bf16x8 v; ushort4 s[2]; } ua, ub;
    float4 p0 = *(const float4*)&xs[row][quad * 8];
    float4 p1 = *(const float4*)&xs[row][quad * 8 + 4];
    float4 p2 = *(const float4*)&xs[row][32 + quad * 8];
    float4 p3 = *(const float4*)&xs[row][32 + quad * 8 + 4];
    ua.s[0] = (ushort4){f2bf(p0.x), f2bf(p0.y), f2bf(p0.z), f2bf(p0.w)};
    ua.s[1] = (ushort4){f2bf(p1.x), f2bf(p1.y), f2bf(p1.z), f2bf(p1.w)};
    ub.s[0] = (ushort4){f2bf(p2.x), f2bf(p2.y), f2bf(p2.z), f2bf(p2.w)};
    ub.s[1] = (ushort4){f2bf(p3.x), f2bf(p3.y), f2bf(p3.z), f2bf(p3.w)};
    a0 = ua.v; a1 = ub.v;
    unsigned short* xp = xb + (size_t)(t0 + row) * 64 + quad * 8;
    *(bf16x8*)xp        = a0;
    *(bf16x8*)(xp + 32) = a1;
  }

  // ---- B-phase: Bx -> bxs ----
  #pragma unroll 2
  for (int n = 0; n < 16; ++n) {
    f32x4 ac[4];
    #pragma unroll
    for (int r = 0; r < 4; ++r) {
      const bf16x8* wv = (const bf16x8*)(WBt + (size_t)((n * 4 + r) * 16 + l15) * 64);
      f32x4 t = {0.f, 0.f, 0.f, 0.f};
      t = __builtin_amdgcn_mfma_f32_16x16x32_bf16(a0, wv[quad],     t, 0, 0, 0);
      t = __builtin_amdgcn_mfma_f32_16x16x32_bf16(a1, wv[quad + 4], t, 0, 0, 0);
      ac[r] = t;
    }
    float part[4] = {0.f, 0.f, 0.f, 0.f};
    #pragma unroll
    for (int r = 0; r < 4; ++r) {
      const float bb = bBs[n * 64 + r * 16 + l15];
      #pragma unroll
      for (int reg = 0; reg < 4; ++reg) {
        const int tl = twl + quad * 4 + reg;
        part[reg] = fmaf(ac[r][reg] + bb, xs[tl][r * 16 + l15], part[reg]);
      }
    }
    #pragma unroll
    for (int off = 1; off < 16; off <<= 1) {
      #pragma unroll
      for (int reg = 0; reg < 4; ++reg)
        part[reg] += __shfl_xor(part[reg], off, 64);
    }
    if (l15 == 0) {
      #pragma unroll
      for (int reg = 0; reg < 4; ++reg)
        bxs[twl + quad * 4 + reg][n] = part[reg];
    }
  }
  __syncthreads();   // bxs ready; xs/bBs dead

  // ---- A-phase: A tile into As ----
  #pragma unroll 2
  for (int ns = 0; ns < 16; ++ns) {
    const bf16x8* wv = (const bf16x8*)(WAt + (size_t)(ns * 16 + l15) * 64);
    f32x4 acc = {0.f, 0.f, 0.f, 0.f};
    acc = __builtin_amdgcn_mfma_f32_16x16x32_bf16(a0, wv[quad],     acc, 0, 0, 0);
    acc = __builtin_amdgcn_mfma_f32_16x16x32_bf16(a1, wv[quad + 4], acc, 0, 0, 0);
    const float bias = bA[ns * 16 + l15];
    #pragma unroll
    for (int r = 0; r < 4; ++r)
      As[(twl + quad * 4 + r) * AS_T + ns * AS_I + l15] = f2bf(acc[r] + bias);
  }
  __syncthreads();

  // ---- scan: wave w owns chunk blockIdx.x*2 + w (16 steps) ----
  {
    bf16x8 wb;          // W in B-operand layout: wb[j] = W[quad*8+j][l15]
    #pragma unroll
    for (int j = 0; j < 8; ++j) wb[j] = (__bf16)((quad * 8 + j == l15) ? 1.f : 0.f);
    f32x4 d = {0.f, 0.f, 0.f, 0.f};
    const int qq = quad & 1;

    #pragma unroll 1
    for (int t = 0; t < CHUNK; ++t) {
      const int tl = twl + t;
      const unsigned short* rp = &As[tl * AS_T + l15 * AS_I];
      uint2 r0 = *(const uint2*)(rp);        // k 0..3
      uint2 r1 = *(const uint2*)(rp + 4);    // k 4..7
      uint2 r2 = *(const uint2*)(rp + 8);    // k 8..11
      uint2 r3 = *(const uint2*)(rp + 12);   // k 12..15

      uint4 abits;
      if (quad == 0)      abits = make_uint4(r0.x, r0.y, r1.x, r1.y);
      else if (quad == 1) abits = make_uint4(r2.x, r2.y, r3.x, r3.y);
      else                abits = make_uint4(0u, 0u, 0u, 0u);
      bf16x8 af = *(bf16x8*)&abits;

      f32x4 z4 = {0.f, 0.f, 0.f, 0.f};
      d = __builtin_amdgcn_mfma_f32_16x16x32_bf16(af, wb, z4, 0, 0, 0);

      float nu = bxs[tl][l15];
      {
        float4 U0 = *(const float4*)&us[w][0];
        float4 U1 = *(const float4*)&us[w][4];
        float4 U2 = *(const float4*)&us[w][8];
        float4 U3 = *(const float4*)&us[w][12];
        nu = fmaf(bflo(r0.x), U0.x, nu); nu = fmaf(bfhi(r0.x), U0.y, nu);
        nu = fmaf(bflo(r0.y), U0.z, nu); nu = fmaf(bfhi(r0.y), U0.w, nu);
        nu = fmaf(bflo(r1.x), U1.x, nu); nu = fmaf(bfhi(r1.x), U1.y, nu);
        nu = fmaf(bflo(r1.y), U1.z, nu); nu = fmaf(bfhi(r1.y), U1.w, nu);
        nu = fmaf(bflo(r2.x), U2.x, nu); nu = fmaf(bfhi(r2.x), U2.y, nu);
        nu = fmaf(bflo(r2.y), U2.z, nu); nu = fmaf(bfhi(r2.y), U2.w, nu);
        nu = fmaf(bflo(r3.x), U3.x, nu); nu = fmaf(bfhi(r3.x), U3.y, nu);
        nu = fmaf(bflo(r3.y), U3.z, nu); nu = fmaf(bfhi(r3.y), U3.w, nu);
      }

      bf16x8 nb;
      nb[0] = (__bf16)__shfl(d[0], (2 * qq + 0) * 16 + l15, 64);
      nb[1] = (__bf16)__shfl(d[1], (2 * qq + 0) * 16 + l15, 64);
      nb[2] = (__bf16)__shfl(d[2], (2 * qq + 0) * 16 + l15, 64);
      nb[3] = (__bf16)__shfl(d[3], (2 * qq + 0) * 16 + l15, 64);
      nb[4] = (__bf16)__shfl(d[0], (2 * qq + 1) * 16 + l15, 64);
      nb[5] = (__bf16)__shfl(d[1], (2 * qq + 1) * 16 + l15, 64);
      nb[6] = (__bf16)__shfl(d[2], (2 * qq + 1) * 16 + l15, 64);
      nb[7] = (__bf16)__shfl(d[3], (2 * qq + 1) * 16 + l15, 64);
      wb = nb;

      if (quad == 0) {
        us[w][l15] = nu;
        bxs[tl][l15] = nu;                 // u prefix in place
      }
      #pragma unroll
      for (int r = 0; r < 4; ++r)
        As[tl * AS_T + (quad * 4 + r) * AS_I + l15] = f2bf(d[r]);
    }

    const int chunk = blockIdx.x * 2 + w;
    #pragma unroll
    for (int r = 0; r < 4; ++r)
      P_ws[(size_t)chunk * 256 + (quad * 4 + r) * 16 + l15] = d[r];
    if (quad == 0) v_ws[(size_t)chunk * DS + l15] = us[w][l15];
  }
  __syncthreads();

  // ---- flush Wt (32x256 bf16 = 1024 uint4) + u (128 float4) coalesced ----
  {
    uint4* Wg = (uint4*)(Wt_ws + (size_t)t0 * 256);
    #pragma unroll 1
    for (int z = 0; z < 8; ++z) {
      const int p4 = z * 128 + tid;
      const int f  = p4 * 8;
      const int t  = f >> 8, i = (f >> 4) & 15, k = f & 15;
      const unsigned short* sp = &As[t * AS_T + i * AS_I + k];
      uint2 lo = *(const uint2*)(sp);
      uint2 hi = *(const uint2*)(sp + 4);
      Wg[p4] = make_uint4(lo.x, lo.y, hi.x, hi.y);
    }
    ((float4*)(u_ws + (size_t)t0 * DS))[tid] = ((const float4*)&bxs[0][0])[tid];
  }
}

// ---------------------------------------------------------------------------
// K3a: supergroup fold.  One wave per supergroup s (128 total): serially
// compose 16 chunk transitions with MFMA: (Q,w) <- (P_c Q, P_c w + v_c).
// ---------------------------------------------------------------------------
__global__ __launch_bounds__(256) void k3a(
    const float* __restrict__ P_ws, const float* __restrict__ v_ws,
    float* __restrict__ Q_ws, float* __restrict__ w_ws)
{
  __shared__ float wsv[4][16];
  const int tid  = threadIdx.x;
  const int lane = tid & 63;
  const int l15  = lane & 15;
  const int quad = lane >> 4;
  const int wv   = tid >> 6;
  const int s    = blockIdx.x * 4 + wv;
  const int qq   = quad & 1;

  if (lane < 16) wsv[wv][lane] = 0.f;
  bf16x8 wb;
  #pragma unroll
  for (int j = 0; j < 8; ++j) wb[j] = (__bf16)((quad * 8 + j == l15) ? 1.f : 0.f);
  f32x4 d = {0.f, 0.f, 0.f, 0.f};

  #pragma unroll 1
  for (int t = 0; t < SG; ++t) {
    const int chunk = s * SG + t;
    float4 p0 = {0.f,0.f,0.f,0.f}, p1 = {0.f,0.f,0.f,0.f};
    if (quad < 2) {
      const float4* pr = (const float4*)(P_ws + (size_t)chunk * 256 + l15 * 16 + quad * 8);
      p0 = pr[0]; p1 = pr[1];
    }
    bf16x8 af;
    af[0] = (__bf16)p0.x; af[1] = (__bf16)p0.y; af[2] = (__bf16)p0.z; af[3] = (__bf16)p0.w;
    af[4] = (__bf16)p1.x; af[5] = (__bf16)p1.y; af[6] = (__bf16)p1.z; af[7] = (__bf16)p1.w;

    f32x4 z4 = {0.f, 0.f, 0.f, 0.f};
    d = __builtin_amdgcn_mfma_f32_16x16x32_bf16(af, wb, z4, 0, 0, 0);

    float part = 0.f;
    if (quad < 2) {
      const float* wrow = &wsv[wv][quad * 8];
      part = p0.x*wrow[0] + p0.y*wrow[1] + p0.z*wrow[2] + p0.w*wrow[3]
           + p1.x*wrow[4] + p1.y*wrow[5] + p1.z*wrow[6] + p1.w*wrow[7];
    }
    part += __shfl_xor(part, 16, 64);
    const float nv = v_ws[(size_t)chunk * DS + l15];

    bf16x8 nb;
    nb[0] = (__bf16)__shfl(d[0], (2 * qq + 0) * 16 + l15, 64);
    nb[1] = (__bf16)__shfl(d[1], (2 * qq + 0) * 16 + l15, 64);
    nb[2] = (__bf16)__shfl(d[2], (2 * qq + 0) * 16 + l15, 64);
    nb[3] = (__bf16)__shfl(d[3], (2 * qq + 0) * 16 + l15, 64);
    nb[4] = (__bf16)__shfl(d[0], (2 * qq + 1) * 16 + l15, 64);
    nb[5] = (__bf16)__shfl(d[1], (2 * qq + 1) * 16 + l15, 64);
    nb[6] = (__bf16)__shfl(d[2], (2 * qq + 1) * 16 + l15, 64);
    nb[7] = (__bf16)__shfl(d[3], (2 * qq + 1) * 16 + l15, 64);
    wb = nb;

    if (quad == 0) wsv[wv][l15] = part + nv;
  }

  #pragma unroll
  for (int r = 0; r < 4; ++r)
    Q_ws[(size_t)s * 256 + (quad * 4 + r) * 16 + l15] = d[r];
  if (quad == 0) w_ws[(size_t)s * DS + l15] = wsv[wv][l15];
}

// ---------------------------------------------------------------------------
// K3b: serial scan over 16 supergroups per batch (8 b x 16 lanes = 128 thr).
// ---------------------------------------------------------------------------
__global__ __launch_bounds__(128) void k3b(
    const float* __restrict__ Q_ws, const float* __restrict__ w_ws,
    float* __restrict__ hbg_ws)
{
  const int tid = threadIdx.x;
  const int b = tid >> 4;
  const int r = tid & 15;
  float h = 0.f;

  #pragma unroll 1
  for (int g = 0; g < 16; ++g) {
    const int s = b * 16 + g;
    const float4* Pr = (const float4*)&Q_ws[(size_t)s * 256 + r * 16];
    float4 c0 = Pr[0], c1 = Pr[1], c2 = Pr[2], c3 = Pr[3];
    const float vc = w_ws[(size_t)s * DS + r];
    hbg_ws[(size_t)s * DS + r] = h;
    float acc = vc;
    acc += c0.x*__shfl(h, 0,16) + c0.y*__shfl(h, 1,16) + c0.z*__shfl(h, 2,16) + c0.w*__shfl(h, 3,16);
    acc += c1.x*__shfl(h, 4,16) + c1.y*__shfl(h, 5,16) + c1.z*__shfl(h, 6,16) + c1.w*__shfl(h, 7,16);
    acc += c2.x*__shfl(h, 8,16) + c2.y*__shfl(h, 9,16) + c2.z*__shfl(h,10,16) + c2.w*__shfl(h,11,16);
    acc += c3.x*__shfl(h,12,16) + c3.y*__shfl(h,13,16) + c3.z*__shfl(h,14,16) + c3.w*__shfl(h,15,16);
    h = acc;
  }
}

// ---------------------------------------------------------------------------
// K3c: within-supergroup replay: entering state of each chunk.  128 groups
// x 16 lanes, serial over 16 chunks.  8 blocks x 256 thr.
// ---------------------------------------------------------------------------
__global__ __launch_bounds__(256) void k3c(
    const float* __restrict__ P_ws, const float* __restrict__ v_ws,
    const float* __restrict__ hbg_ws, float* __restrict__ hb_ws)
{
  const int tid = threadIdx.x;
  const int s = blockIdx.x * 16 + (tid >> 4);
  const int r = tid & 15;
  float h = hbg_ws[(size_t)s * DS + r];

  #pragma unroll 1
  for (int t = 0; t < SG; ++t) {
    const int chunk = s * SG + t;
    const float4* Pr = (const float4*)&P_ws[(size_t)chunk * 256 + r * 16];
    float4 c0 = Pr[0], c1 = Pr[1], c2 = Pr[2], c3 = Pr[3];
    const float vc = v_ws[(size_t)chunk * DS + r];
    hb_ws[(size_t)chunk * DS + r] = h;
    float acc = vc;
    acc += c0.x*__shfl(h, 0,16) + c0.y*__shfl(h, 1,16) + c0.z*__shfl(h, 2,16) + c0.w*__shfl(h, 3,16);
    acc += c1.x*__shfl(h, 4,16) + c1.y*__shfl(h, 5,16) + c1.z*__shfl(h, 6,16) + c1.w*__shfl(h, 7,16);
    acc += c2.x*__shfl(h, 8,16) + c2.y*__shfl(h, 9,16) + c2.z*__shfl(h,10,16) + c2.w*__shfl(h,11,16);
    acc += c3.x*__shfl(h,12,16) + c3.y*__shfl(h,13,16) + c3.z*__shfl(h,14,16) + c3.w*__shfl(h,15,16);
    h = acc;
  }
}

// ---------------------------------------------------------------------------
// G2: per block 64 t.  Phase 1: hs = W_t h_entry + u_t into LDS.
// Phase 2: out = sum_n (x@WC + bC)[n,d] * hs[n] via MFMA.
// ---------------------------------------------------------------------------
__global__ __launch_bounds__(256) void g2(
    const unsigned short* __restrict__ xb, const unsigned short* __restrict__ WCt,
    const float* __restrict__ bC, const unsigned short* __restrict__ Wt_ws,
    const float* __restrict__ u_ws, const float* __restrict__ hb_ws,
    float* __restrict__ out)
{
  __shared__ float hsh[64][17];
  __shared__ float bCs[1024];
  const int tid  = threadIdx.x;
  const int lane = tid & 63;
  const int l15  = lane & 15;
  const int quad = lane >> 4;
  const int w    = tid >> 6;
  const int t0   = blockIdx.x * 64;
  const int twl  = w * 16;

  ((float4*)bCs)[tid] = ((const float4*)bC)[tid];

  #pragma unroll
  for (int z = 0; z < 4; ++z) {
    const int gcell = z * 256 + tid;
    const int tl = gcell >> 4, i = gcell & 15;
    const int t = t0 + tl;
    const uint4* wr = (const uint4*)(Wt_ws + (size_t)t * 256 + i * 16);
    uint4 wa = wr[0], wbv = wr[1];
    const float4* hp = (const float4*)(hb_ws + (size_t)(t >> 4) * DS);  // CHUNK=16
    float4 h0 = hp[0], h1 = hp[1], h2 = hp[2], h3 = hp[3];
    float acc = u_ws[(size_t)t * DS + i];
    acc = fmaf(bflo(wa.x),  h0.x, acc); acc = fmaf(bfhi(wa.x),  h0.y, acc);
    acc = fmaf(bflo(wa.y),  h0.z, acc); acc = fmaf(bfhi(wa.y),  h0.w, acc);
    acc = fmaf(bflo(wa.z),  h1.x, acc); acc = fmaf(bfhi(wa.z),  h1.y, acc);
    acc = fmaf(bflo(wa.w),  h1.z, acc); acc = fmaf(bfhi(wa.w),  h1.w, acc);
    acc = fmaf(bflo(wbv.x), h2.x, acc); acc = fmaf(bfhi(wbv.x), h2.y, acc);
    acc = fmaf(bflo(wbv.y), h2.z, acc); acc = fmaf(bfhi(wbv.y), h2.w, acc);
    acc = fmaf(bflo(wbv.z), h3.x, acc); acc = fmaf(bfhi(wbv.z), h3.y, acc);
    acc = fmaf(bflo(wbv.w), h3.z, acc); acc = fmaf(bfhi(wbv.w), h3.w, acc);
    hsh[tl][i] = acc;
  }

  const bf16x8* xv = (const bf16x8*)(xb + (size_t)(t0 + twl + l15) * 64);
  bf16x8 a0 = xv[quad];
  bf16x8 a1 = xv[quad + 4];
  __syncthreads();

  f32x4 ota[4];
  #pragma unroll
  for (int r = 0; r < 4; ++r) ota[r] = (f32x4){0.f, 0.f, 0.f, 0.f};

  #pragma unroll 2
  for (int n = 0; n < 16; ++n) {
    f32x4 ac[4];
    #pragma unroll
    for (int r = 0; r < 4; ++r) {
      const bf16x8* wv = (const bf16x8*)(WCt + (size_t)((n * 4 + r) * 16 + l15) * 64);
      f32x4 t = {0.f, 0.f, 0.f, 0.f};
      t = __builtin_amdgcn_mfma_f32_16x16x32_bf16(a0, wv[quad],     t, 0, 0, 0);
      t = __builtin_amdgcn_mfma_f32_16x16x32_bf16(a1, wv[quad + 4], t, 0, 0, 0);
      ac[r] = t;
    }
    float hn[4];
    #pragma unroll
    for (int reg = 0; reg < 4; ++reg) hn[reg] = hsh[twl + quad * 4 + reg][n];
    #pragma unroll
    for (int r = 0; r < 4; ++r) {
      const float bc = bCs[n * 64 + r * 16 + l15];
      #pragma unroll
      for (int reg = 0; reg < 4; ++reg)
        ota[r][reg] = fmaf(ac[r][reg] + bc, hn[reg], ota[r][reg]);
    }
  }

  #pragma unroll
  for (int r = 0; r < 4; ++r)
    #pragma unroll
    for (int reg = 0; reg < 4; ++reg)
      out[(size_t)(t0 + twl + quad * 4 + reg) * DM + r * 16 + l15] = ota[r][reg];
}

// ---------------------------------------------------------------------------
extern "C" void kernel_launch(void* const* d_in, const int* in_sizes, int n_in,
                              void* d_out, int out_size, void* d_ws, size_t ws_size,
                              hipStream_t stream) {
  const float* x  = (const float*)d_in[0];
  const float* WA = (const float*)d_in[1];
  const float* bA = (const float*)d_in[2];
  const float* WB = (const float*)d_in[3];
  const float* bB = (const float*)d_in[4];
  const float* WC = (const float*)d_in[5];
  const float* bC = (const float*)d_in[6];
  float* out = (float*)d_out;

  float* ws     = (float*)d_ws;
  float* P_ws   = ws;                               // NCHT*256 (2 MB)
  float* v_ws   = P_ws   + (size_t)NCHT * 256;      // NCHT*16
  float* u_ws   = v_ws   + (size_t)NCHT * DS;       // BS*16
  float* Q_ws   = u_ws   + (size_t)BS * DS;         // NSG*256
  float* w_ws   = Q_ws   + (size_t)NSG * 256;       // NSG*16
  float* hbg_ws = w_ws   + (size_t)NSG * DS;        // NSG*16
  float* hb_ws  = hbg_ws + (size_t)NSG * DS;        // NCHT*16
  unsigned short* xb    = (unsigned short*)(hb_ws + (size_t)NCHT * DS);
  unsigned short* WAt   = xb  + (size_t)BS * 64;    // 16384
  unsigned short* WBt   = WAt + 256 * 64;           // 65536
  unsigned short* WCt   = WBt + 1024 * 64;          // 65536
  unsigned short* Wt_ws = WCt + 1024 * 64;          // BS*256 (16.8 MB)

  k0_castw<<<576,      256, 0, stream>>>(WA, WB, WC, WAt, WBt, WCt);
  g1      <<<BS / 32,  128, 0, stream>>>(x, WBt, bB, WAt, bA, xb, Wt_ws, u_ws, P_ws, v_ws);
  k3a     <<<NSG / 4,  256, 0, stream>>>(P_ws, v_ws, Q_ws, w_ws);
  k3b     <<<1,        128, 0, stream>>>(Q_ws, w_ws, hbg_ws);
  k3c     <<<NSG / 16, 256, 0, stream>>>(P_ws, v_ws, hbg_ws, hb_ws);
  g2      <<<BS / 64,  256, 0, stream>>>(xb, WCt, bC, Wt_ws, u_ws, hb_ws, out);
}